// Round 1
// baseline (20343.388 us; speedup 1.0000x reference)
//
#include <hip/hip_runtime.h>
#include <hip/hip_bf16.h>
#include <stdint.h>

typedef __hip_bfloat16 bf16;

__device__ __forceinline__ float b2f(bf16 v) { return __bfloat162float(v); }
__device__ __forceinline__ bf16 f2b(float v) { return __float2bfloat16(v); }

// ---------------------------------------------------------------------------
// GEMM: C[M,N] = act(A[M,K] @ W[N,K]^T + bias[N])
// A: f32 or bf16 (a_bf16). C: f32 or bf16 (c_bf16). relu optional.
// store_mode 1: rows are (m*32+b), stored to row (b*31+m)  [final logits transpose]
// 64x64 tile, BK=16, 256 threads, 4x4 per thread, f32 FMA (round-0 baseline).
// ---------------------------------------------------------------------------
__global__ __launch_bounds__(256) void gemm_kernel(
    const void* __restrict__ A, const float* __restrict__ W,
    const float* __restrict__ bias, void* __restrict__ C,
    int M, int N, int K, int a_bf16, int c_bf16, int relu, int store_mode)
{
    __shared__ float As[16][68];
    __shared__ float Bs[16][68];
    const int tid = threadIdx.x;
    const int m0 = blockIdx.y * 64;
    const int n0 = blockIdx.x * 64;
    const int tx = tid & 15, ty = tid >> 4;
    const float* Af = (const float*)A;
    const bf16*  Ab = (const bf16*)A;
    float acc[4][4] = {};
    for (int k0 = 0; k0 < K; k0 += 16) {
#pragma unroll
        for (int t = 0; t < 4; ++t) {
            int idx = tid + 256 * t;
            int mi = idx >> 4, kk = idx & 15;
            int gm = m0 + mi, gk = k0 + kk;
            float v = 0.f;
            if (gm < M && gk < K)
                v = a_bf16 ? b2f(Ab[(size_t)gm * K + gk]) : Af[(size_t)gm * K + gk];
            As[kk][mi] = v;
        }
#pragma unroll
        for (int t = 0; t < 4; ++t) {
            int idx = tid + 256 * t;
            int ni = idx >> 4, kk = idx & 15;
            int gn = n0 + ni, gk = k0 + kk;
            float v = 0.f;
            if (gn < N && gk < K) v = W[(size_t)gn * K + gk];
            Bs[kk][ni] = v;
        }
        __syncthreads();
#pragma unroll
        for (int kk = 0; kk < 16; ++kk) {
            const float4 a4 = *(const float4*)&As[kk][ty * 4];
            const float4 b4 = *(const float4*)&Bs[kk][tx * 4];
            const float ar[4] = {a4.x, a4.y, a4.z, a4.w};
            const float br[4] = {b4.x, b4.y, b4.z, b4.w};
#pragma unroll
            for (int i = 0; i < 4; ++i)
#pragma unroll
                for (int j = 0; j < 4; ++j) acc[i][j] += ar[i] * br[j];
        }
        __syncthreads();
    }
#pragma unroll
    for (int i = 0; i < 4; ++i) {
        int m = m0 + ty * 4 + i;
        if (m >= M) continue;
        size_t orow = (size_t)m;
        if (store_mode == 1) { int mm = m >> 5, bb = m & 31; orow = (size_t)bb * 31 + mm; }
#pragma unroll
        for (int j = 0; j < 4; ++j) {
            int n = n0 + tx * 4 + j;
            if (n >= N) continue;
            float v = acc[i][j] + bias[n];
            if (relu) v = fmaxf(v, 0.f);
            if (c_bf16) ((bf16*)C)[orow * N + n] = f2b(v);
            else        ((float*)C)[orow * N + n] = v;
        }
    }
}

// ---------------------------------------------------------------------------
// Self-attention over qkv (rows = cm*1024, cols 1536: q|k|v), T=32, dh=64.
// One block (256 thr = 4 waves) per (m_local*32+b, head). Causal + key-pad mask.
// ---------------------------------------------------------------------------
__global__ __launch_bounds__(256) void self_attn_kernel(
    const bf16* __restrict__ qkv, const int* __restrict__ input_ids,
    bf16* __restrict__ attn_out, int cm)
{
    const int blk = blockIdx.x;
    const int h = blk & 7;
    const int mb = blk >> 3;           // m_local*32 + b
    const int b = mb & 31;
    __shared__ float qs[32][65], ks[32][65], vs[32][65];
    __shared__ int kpm[32];
    const int tid = threadIdx.x;
    const size_t rowbase = (size_t)mb * 32;
    for (int idx = tid; idx < 2048; idx += 256) {
        int r = idx >> 6, c = idx & 63;
        size_t base = (rowbase + r) * 1536;
        qs[r][c] = b2f(qkv[base + h * 64 + c]);
        ks[r][c] = b2f(qkv[base + 512 + h * 64 + c]);
        vs[r][c] = b2f(qkv[base + 1024 + h * 64 + c]);
    }
    if (tid < 32) kpm[tid] = (input_ids[b * 32 + tid] == 0);
    __syncthreads();
    const int lane = tid & 63, wave = tid >> 6;
    const int jj = lane & 31;
    for (int rr = 0; rr < 8; ++rr) {
        int i = wave * 8 + rr;
        float s = 0.f;
#pragma unroll
        for (int d = 0; d < 64; ++d) s += qs[i][d] * ks[jj][d];
        s *= 0.125f;
        if (jj > i) s = -1e9f;
        if (kpm[jj]) s = -1e9f;
        float mx = s;
        for (int o = 16; o; o >>= 1) mx = fmaxf(mx, __shfl_xor(mx, o, 32));
        float e = expf(s - mx);
        float sm = e;
        for (int o = 16; o; o >>= 1) sm += __shfl_xor(sm, o, 32);
        float p = e / sm;
        float acc = 0.f;
#pragma unroll
        for (int j = 0; j < 32; ++j) {
            float pj = __shfl(p, j, 32);
            acc += pj * vs[j][lane];
        }
        attn_out[(rowbase + i) * 512 + h * 64 + lane] = f2b(acc);
    }
}

// ---------------------------------------------------------------------------
// Cross-attention: q rows = cm*1024 (cols 512), kv rows = cm*32*27 (cols 1024: k|v).
// LK=27, no masks.
// ---------------------------------------------------------------------------
__global__ __launch_bounds__(256) void cross_attn_kernel(
    const bf16* __restrict__ q, const bf16* __restrict__ kv,
    bf16* __restrict__ attn_out, int cm)
{
    const int blk = blockIdx.x;
    const int h = blk & 7;
    const int mb = blk >> 3;
    __shared__ float qs[32][65], ks[27][65], vs[27][65];
    const int tid = threadIdx.x;
    const size_t qrow = (size_t)mb * 32;
    const size_t kvrow = (size_t)mb * 27;
    for (int idx = tid; idx < 2048; idx += 256) {
        int r = idx >> 6, c = idx & 63;
        qs[r][c] = b2f(q[(qrow + r) * 512 + h * 64 + c]);
    }
    for (int idx = tid; idx < 27 * 64; idx += 256) {
        int r = idx >> 6, c = idx & 63;
        size_t base = (kvrow + r) * 1024;
        ks[r][c] = b2f(kv[base + h * 64 + c]);
        vs[r][c] = b2f(kv[base + 512 + h * 64 + c]);
    }
    __syncthreads();
    const int lane = tid & 63, wave = tid >> 6;
    const int jj = lane & 31;
    for (int rr = 0; rr < 8; ++rr) {
        int i = wave * 8 + rr;
        float s;
        if (jj < 27) {
            s = 0.f;
#pragma unroll
            for (int d = 0; d < 64; ++d) s += qs[i][d] * ks[jj][d];
            s *= 0.125f;
        } else s = -1e30f;
        float mx = s;
        for (int o = 16; o; o >>= 1) mx = fmaxf(mx, __shfl_xor(mx, o, 32));
        float e = expf(s - mx);
        float sm = e;
        for (int o = 16; o; o >>= 1) sm += __shfl_xor(sm, o, 32);
        float p = e / sm;
        float acc = 0.f;
#pragma unroll
        for (int j = 0; j < 27; ++j) {
            float pj = __shfl(p, j, 32);
            acc += pj * vs[j][lane];
        }
        attn_out[(qrow + i) * 512 + h * 64 + lane] = f2b(acc);
    }
}

// ---------------------------------------------------------------------------
// LayerNorm over D=512. One wave per row, 4 rows per block.
// ---------------------------------------------------------------------------
__global__ __launch_bounds__(256) void ln_kernel(
    const float* __restrict__ x, const float* __restrict__ g,
    const float* __restrict__ b_, float* __restrict__ out, int rows)
{
    int row = blockIdx.x * 4 + (threadIdx.x >> 6);
    if (row >= rows) return;
    int lane = threadIdx.x & 63;
    const float* xr = x + (size_t)row * 512;
    float v[8];
    float sum = 0.f;
#pragma unroll
    for (int k = 0; k < 8; ++k) { v[k] = xr[lane + 64 * k]; sum += v[k]; }
    for (int o = 32; o; o >>= 1) sum += __shfl_xor(sum, o, 64);
    float mean = sum * (1.f / 512.f);
    float vs = 0.f;
#pragma unroll
    for (int k = 0; k < 8; ++k) { float d = v[k] - mean; vs += d * d; }
    for (int o = 32; o; o >>= 1) vs += __shfl_xor(vs, o, 64);
    float rstd = rsqrtf(vs * (1.f / 512.f) + 1e-5f);
    float* orow = out + (size_t)row * 512;
#pragma unroll
    for (int k = 0; k < 8; ++k) {
        int c = lane + 64 * k;
        orow[c] = (v[k] - mean) * rstd * g[c] + b_[c];
    }
}

// x = LN(x + branch)   (branch bf16)
__global__ __launch_bounds__(256) void ln_res_kernel(
    float* __restrict__ x, const bf16* __restrict__ br,
    const float* __restrict__ g, const float* __restrict__ b_, int rows)
{
    int row = blockIdx.x * 4 + (threadIdx.x >> 6);
    if (row >= rows) return;
    int lane = threadIdx.x & 63;
    float* xr = x + (size_t)row * 512;
    const bf16* brr = br + (size_t)row * 512;
    float v[8];
    float sum = 0.f;
#pragma unroll
    for (int k = 0; k < 8; ++k) {
        int c = lane + 64 * k;
        v[k] = xr[c] + b2f(brr[c]);
        sum += v[k];
    }
    for (int o = 32; o; o >>= 1) sum += __shfl_xor(sum, o, 64);
    float mean = sum * (1.f / 512.f);
    float vs = 0.f;
#pragma unroll
    for (int k = 0; k < 8; ++k) { float d = v[k] - mean; vs += d * d; }
    for (int o = 32; o; o >>= 1) vs += __shfl_xor(vs, o, 64);
    float rstd = rsqrtf(vs * (1.f / 512.f) + 1e-5f);
#pragma unroll
    for (int k = 0; k < 8; ++k) {
        int c = lane + 64 * k;
        xr[c] = (v[k] - mean) * rstd * g[c] + b_[c];
    }
}

// env row build + LN (mem_g/mem_b). rows = B*T*9 = 9216.
__global__ __launch_bounds__(256) void env_ln_kernel(
    const float* __restrict__ astate, const int* __restrict__ atok,
    const float* __restrict__ emb, const int* __restrict__ goal,
    const float* __restrict__ g, const float* __restrict__ b_, float* __restrict__ env)
{
    int row = blockIdx.x * 4 + (threadIdx.x >> 6);
    if (row >= 9216) return;
    int lane = threadIdx.x & 63;
    int s9 = row % 9;
    int bt = row / 9;   // b*32 + t
    float v[8];
    if (s9 < 8) {
        int ar = bt * 8 + s9;
        float msk = (atok[ar] != -1) ? 1.f : 0.f;
#pragma unroll
        for (int k = 0; k < 8; ++k) v[k] = astate[(size_t)ar * 512 + lane + 64 * k] * msk;
    } else {
        int gi = goal[bt >> 5];
#pragma unroll
        for (int k = 0; k < 8; ++k) v[k] = emb[(size_t)gi * 512 + lane + 64 * k];
    }
    float sum = 0.f;
#pragma unroll
    for (int k = 0; k < 8; ++k) sum += v[k];
    for (int o = 32; o; o >>= 1) sum += __shfl_xor(sum, o, 64);
    float mean = sum * (1.f / 512.f);
    float vs = 0.f;
#pragma unroll
    for (int k = 0; k < 8; ++k) { float d = v[k] - mean; vs += d * d; }
    for (int o = 32; o; o >>= 1) vs += __shfl_xor(vs, o, 64);
    float rstd = rsqrtf(vs * (1.f / 512.f) + 1e-5f);
    float* orow = env + (size_t)row * 512;
#pragma unroll
    for (int k = 0; k < 8; ++k) {
        int c = lane + 64 * k;
        orow[c] = (v[k] - mean) * rstd * g[c] + b_[c];
    }
}

// mems[(m*32+b)*27 + j] = env[(b*32 + clip(m-1+j/9,0,31))*9 + j%9]  (bf16)
__global__ void mems_kernel(const float* __restrict__ env, bf16* __restrict__ mems)
{
    int row = blockIdx.x;               // 31*32*27 = 26784
    int j = row % 27;
    int mb = row / 27;
    int m = mb >> 5, b = mb & 31;
    int gidx = j / 9, sp = j % 9;
    int t = m - 1 + gidx;
    t = t < 0 ? 0 : (t > 31 ? 31 : t);
    const float* src = env + ((size_t)(b * 32 + t) * 9 + sp) * 512;
    bf16* dst = mems + (size_t)row * 512;
    for (int c = threadIdx.x; c < 512; c += 64) dst[c] = f2b(src[c]);
}

// xcat[r][0:512]=emb[ids[r]], [512:515]=ego[b]
__global__ void xcat_kernel(const int* __restrict__ ids, const float* __restrict__ ego,
                            const float* __restrict__ emb, float* __restrict__ xcat)
{
    int row = blockIdx.x;   // 1024
    int b = row >> 5;
    int id = ids[row];
    float* dst = xcat + (size_t)row * 515;
    const float* src = emb + (size_t)id * 512;
    for (int c = threadIdx.x; c < 512; c += 256) dst[c] = src[c];
    if (threadIdx.x < 3) dst[512 + threadIdx.x] = ego[b * 3 + threadIdx.x];
}

// acat[r][0:512]=emb[mask?tok:PAD], [512:517]=afeat[r]
__global__ void acat_kernel(const int* __restrict__ atok, const float* __restrict__ afeat,
                            const float* __restrict__ emb, float* __restrict__ acat)
{
    int row = blockIdx.x;   // 8192
    int tok = atok[row];
    int id = (tok != -1) ? tok : 0;
    float* dst = acat + (size_t)row * 517;
    const float* src = emb + (size_t)id * 512;
    for (int c = threadIdx.x; c < 512; c += 256) dst[c] = src[c];
    if (threadIdx.x < 5) dst[512 + threadIdx.x] = afeat[(size_t)row * 5 + threadIdx.x];
}

// broadcast self_state (1024x512) to x (cm*1024 x 512)
__global__ void initx_kernel(const float* __restrict__ ss, float* __restrict__ x, int total)
{
    int i = blockIdx.x * 256 + threadIdx.x;
    if (i < total) x[i] = ss[i & 524287];
}

// sel[(m0+ml)*32+b] = x[(ml*32+b)*32 + (m0+ml+1)]
__global__ void sel_kernel(const float* __restrict__ x, float* __restrict__ sel, int m0, int cm)
{
    int row = blockIdx.x;   // cm*32
    int ml = row >> 5, b = row & 31;
    int m = m0 + ml;
    const float* src = x + ((size_t)(ml * 32 + b) * 32 + (m + 1)) * 512;
    float* dst = sel + ((size_t)m * 32 + b) * 512;
    for (int c = threadIdx.x; c < 512; c += 256) dst[c] = src[c];
}

__global__ void fill_kernel(float* __restrict__ o, int n, float v)
{
    int i = blockIdx.x * 256 + threadIdx.x;
    if (i < n) o[i] = v;
}

// ---------------------------------------------------------------------------
extern "C" void kernel_launch(void* const* d_in, const int* in_sizes, int n_in,
                              void* d_out, int out_size, void* d_ws, size_t ws_size,
                              hipStream_t stream)
{
    float* out = (float*)d_out;
    if (n_in < 40) {
        fill_kernel<<<(out_size + 255) / 256, 256, 0, stream>>>(out, out_size, 1e6f);
        return;
    }
    const int*   input_ids = (const int*)d_in[0];
    const float* ego       = (const float*)d_in[1];
    const int*   atok      = (const int*)d_in[2];
    const float* afeat     = (const float*)d_in[3];
    const int*   goal      = (const int*)d_in[4];
    const float* emb       = (const float*)d_in[5];
    const float* se_w1 = (const float*)d_in[6];
    const float* se_b1 = (const float*)d_in[7];
    const float* se_w2 = (const float*)d_in[8];
    const float* se_b2 = (const float*)d_in[9];
    const float* be_w1 = (const float*)d_in[10];
    const float* be_b1 = (const float*)d_in[11];
    const float* be_w2 = (const float*)d_in[12];
    const float* be_b2 = (const float*)d_in[13];
    const float* in_g  = (const float*)d_in[14];
    const float* in_b  = (const float*)d_in[15];
    const float* mem_g = (const float*)d_in[16];
    const float* mem_b = (const float*)d_in[17];
    const float* outn_g = (const float*)d_in[18];
    const float* outn_b = (const float*)d_in[19];
    const float* sa_in_w  = (const float*)d_in[20];
    const float* sa_in_b  = (const float*)d_in[21];
    const float* sa_out_w = (const float*)d_in[22];
    const float* sa_out_b = (const float*)d_in[23];
    const float* ca_in_w  = (const float*)d_in[24];
    const float* ca_in_b  = (const float*)d_in[25];
    const float* ca_out_w = (const float*)d_in[26];
    const float* ca_out_b = (const float*)d_in[27];
    const float* ff_w1 = (const float*)d_in[28];
    const float* ff_b1 = (const float*)d_in[29];
    const float* ff_w2 = (const float*)d_in[30];
    const float* ff_b2 = (const float*)d_in[31];
    const float* ln1_g = (const float*)d_in[32];
    const float* ln1_b = (const float*)d_in[33];
    const float* ln2_g = (const float*)d_in[34];
    const float* ln2_b = (const float*)d_in[35];
    const float* ln3_g = (const float*)d_in[36];
    const float* ln3_b = (const float*)d_in[37];
    const float* proj_w = (const float*)d_in[38];
    const float* proj_b = (const float*)d_in[39];

    auto ALIGN = [](size_t b) { return (b + 255) & ~(size_t)255; };
    uintptr_t base = (uintptr_t)d_ws;
    uintptr_t cur = (base + 255) & ~(uintptr_t)255;
    auto alloc = [&](size_t bytes) -> char* {
        char* r = (char*)cur; cur += (bytes + 255) & ~(size_t)255; return r;
    };

    // persistent
    float* self_state = (float*)alloc((size_t)1024 * 512 * 4);
    bf16*  mems       = (bf16*) alloc((size_t)26784 * 512 * 2);
    float* sel        = (float*)alloc((size_t)992 * 512 * 4);
    float* sel_ln     = (float*)alloc((size_t)992 * 512 * 4);
    uintptr_t big = cur;

    size_t setup_need =
        ALIGN((size_t)1024 * 515 * 4) + ALIGN((size_t)1024 * 512 * 4) + ALIGN((size_t)1024 * 512 * 4) +
        ALIGN((size_t)8192 * 517 * 4) + ALIGN((size_t)8192 * 512 * 4) + ALIGN((size_t)8192 * 512 * 4) +
        ALIGN((size_t)9216 * 512 * 4);
    auto chunk_need = [&](int c) -> size_t {
        return ALIGN((size_t)c * 1024 * 512 * 4)    // x (f32)
             + ALIGN((size_t)c * 1024 * 1536 * 2)   // qkv / cross-q (bf16)
             + ALIGN((size_t)c * 1024 * 512 * 2)    // attn raw (bf16)
             + ALIGN((size_t)c * 1024 * 512 * 2)    // branch (bf16)
             + ALIGN((size_t)c * 1024 * 2048 * 2)   // ff1 (bf16)
             + ALIGN((size_t)c * 864 * 1024 * 2);   // cross kv (bf16)
    };
    int CH = 0;
    if (ws_size > (size_t)(big - base) + 4096) {
        size_t avail = ws_size - (size_t)(big - base) - 4096;
        for (int c = 31; c >= 1; --c)
            if (setup_need <= avail && chunk_need(c) <= avail) { CH = c; break; }
    }
    if (!CH) {   // diagnostic sentinel: workspace too small
        fill_kernel<<<(out_size + 255) / 256, 256, 0, stream>>>(out, out_size, 1e6f);
        return;
    }

    auto launch_gemm = [&](const void* A, int a_bf16, const float* W, const float* bias,
                           void* C, int c_bf16, int M, int N, int K, int relu, int smode) {
        dim3 g((N + 63) / 64, (M + 63) / 64);
        gemm_kernel<<<g, 256, 0, stream>>>(A, W, bias, C, M, N, K, a_bf16, c_bf16, relu, smode);
    };

    // ---------------- setup: encoders, env, mems ----------------
    {
        uintptr_t sp = big;
        auto salloc = [&](size_t b) -> char* { char* r = (char*)sp; sp += ALIGN(b); return r; };
        float* xcat   = (float*)salloc((size_t)1024 * 515 * 4);
        float* h1     = (float*)salloc((size_t)1024 * 512 * 4);
        float* fused  = (float*)salloc((size_t)1024 * 512 * 4);
        float* acat   = (float*)salloc((size_t)8192 * 517 * 4);
        float* ah1    = (float*)salloc((size_t)8192 * 512 * 4);
        float* astate = (float*)salloc((size_t)8192 * 512 * 4);
        float* env    = (float*)salloc((size_t)9216 * 512 * 4);

        xcat_kernel<<<1024, 256, 0, stream>>>(input_ids, ego, emb, xcat);
        launch_gemm(xcat, 0, se_w1, se_b1, h1, 0, 1024, 512, 515, 1, 0);
        launch_gemm(h1, 0, se_w2, se_b2, fused, 0, 1024, 512, 512, 0, 0);
        ln_kernel<<<256, 256, 0, stream>>>(fused, in_g, in_b, self_state, 1024);

        acat_kernel<<<8192, 256, 0, stream>>>(atok, afeat, emb, acat);
        launch_gemm(acat, 0, be_w1, be_b1, ah1, 0, 8192, 512, 517, 1, 0);
        launch_gemm(ah1, 0, be_w2, be_b2, astate, 0, 8192, 512, 512, 0, 0);
        env_ln_kernel<<<2304, 256, 0, stream>>>(astate, atok, emb, goal, mem_g, mem_b, env);
        mems_kernel<<<26784, 64, 0, stream>>>(env, mems);
    }

    // ---------------- decode: chunks over the 31 mems ----------------
    {
        uintptr_t sp = big;
        auto salloc = [&](size_t b) -> char* { char* r = (char*)sp; sp += ALIGN(b); return r; };
        float* x     = (float*)salloc((size_t)CH * 1024 * 512 * 4);
        bf16*  qkv   = (bf16*) salloc((size_t)CH * 1024 * 1536 * 2);
        bf16*  araw  = (bf16*) salloc((size_t)CH * 1024 * 512 * 2);
        bf16*  brnch = (bf16*) salloc((size_t)CH * 1024 * 512 * 2);
        bf16*  ff1b  = (bf16*) salloc((size_t)CH * 1024 * 2048 * 2);
        bf16*  kv    = (bf16*) salloc((size_t)CH * 864 * 1024 * 2);

        for (int m0 = 0; m0 < 31; m0 += CH) {
            int cm = (31 - m0) < CH ? (31 - m0) : CH;
            int Mr = cm * 1024;
            initx_kernel<<<cm * 2048, 256, 0, stream>>>(self_state, x, Mr * 512);
            for (int l = 0; l < 4; ++l) {
                // --- self attention ---
                launch_gemm(x, 0, sa_in_w + (size_t)l * 1536 * 512, sa_in_b + l * 1536,
                            qkv, 1, Mr, 1536, 512, 0, 0);
                self_attn_kernel<<<cm * 32 * 8, 256, 0, stream>>>(qkv, input_ids, araw, cm);
                launch_gemm(araw, 1, sa_out_w + (size_t)l * 512 * 512, sa_out_b + l * 512,
                            brnch, 1, Mr, 512, 512, 0, 0);
                ln_res_kernel<<<(Mr + 3) / 4, 256, 0, stream>>>(x, brnch, ln1_g + l * 512, ln1_b + l * 512, Mr);
                // --- cross attention ---
                const float* wc = ca_in_w + (size_t)l * 1536 * 512;
                const float* bc = ca_in_b + l * 1536;
                launch_gemm(x, 0, wc, bc, qkv, 1, Mr, 512, 512, 0, 0);                      // q (reuse qkv buf)
                launch_gemm(mems + (size_t)m0 * 864 * 512, 1, wc + (size_t)512 * 512, bc + 512,
                            kv, 1, cm * 864, 1024, 512, 0, 0);                              // k|v
                cross_attn_kernel<<<cm * 32 * 8, 256, 0, stream>>>(qkv, kv, araw, cm);
                launch_gemm(araw, 1, ca_out_w + (size_t)l * 512 * 512, ca_out_b + l * 512,
                            brnch, 1, Mr, 512, 512, 0, 0);
                ln_res_kernel<<<(Mr + 3) / 4, 256, 0, stream>>>(x, brnch, ln2_g + l * 512, ln2_b + l * 512, Mr);
                // --- FFN ---
                launch_gemm(x, 0, ff_w1 + (size_t)l * 2048 * 512, ff_b1 + l * 2048,
                            ff1b, 1, Mr, 2048, 512, 1, 0);
                launch_gemm(ff1b, 1, ff_w2 + (size_t)l * 512 * 2048, ff_b2 + l * 512,
                            brnch, 1, Mr, 512, 2048, 0, 0);
                ln_res_kernel<<<(Mr + 3) / 4, 256, 0, stream>>>(x, brnch, ln3_g + l * 512, ln3_b + l * 512, Mr);
            }
            sel_kernel<<<cm * 32, 256, 0, stream>>>(x, sel, m0, cm);
        }
    }

    // ---------------- final: LN + vocab projection (+ transpose store) ----------------
    ln_kernel<<<248, 256, 0, stream>>>(sel, outn_g, outn_b, sel_ln, 992);
    launch_gemm(sel_ln, 0, proj_w, proj_b, out, 0, 992, 4096, 512, 0, 1);
}

// Round 2
// 5662.928 us; speedup vs baseline: 3.5924x; 3.5924x over previous
//
#include <hip/hip_runtime.h>
#include <hip/hip_bf16.h>
#include <stdint.h>

typedef __hip_bfloat16 bf16;
typedef __attribute__((ext_vector_type(8))) short bf16x8;
typedef __attribute__((ext_vector_type(4))) float f32x4;

__device__ __forceinline__ float b2f(bf16 v) { return __bfloat162float(v); }
__device__ __forceinline__ bf16 f2b(float v) { return __float2bfloat16(v); }
__device__ __forceinline__ unsigned short f2bu(float v) {
    bf16 h = __float2bfloat16(v);
    return *(unsigned short*)&h;
}

__device__ __forceinline__ void gload_lds16(const void* g, void* l) {
    __builtin_amdgcn_global_load_lds((const __attribute__((address_space(1))) void*)g,
                                     (__attribute__((address_space(3))) void*)l, 16, 0, 0);
}

// ---------------------------------------------------------------------------
// f32 fallback GEMM (only for K=515/517 encoder layers).
// C[M,N] = act(A[M,K] @ W[N,K]^T + bias)
// ---------------------------------------------------------------------------
__global__ __launch_bounds__(256) void gemm_kernel(
    const void* __restrict__ A, const float* __restrict__ W,
    const float* __restrict__ bias, void* __restrict__ C,
    int M, int N, int K, int a_bf16, int c_bf16, int relu, int store_mode)
{
    __shared__ float As[16][68];
    __shared__ float Bs[16][68];
    const int tid = threadIdx.x;
    const int m0 = blockIdx.y * 64;
    const int n0 = blockIdx.x * 64;
    const int tx = tid & 15, ty = tid >> 4;
    const float* Af = (const float*)A;
    const bf16*  Ab = (const bf16*)A;
    float acc[4][4] = {};
    for (int k0 = 0; k0 < K; k0 += 16) {
#pragma unroll
        for (int t = 0; t < 4; ++t) {
            int idx = tid + 256 * t;
            int mi = idx >> 4, kk = idx & 15;
            int gm = m0 + mi, gk = k0 + kk;
            float v = 0.f;
            if (gm < M && gk < K)
                v = a_bf16 ? b2f(Ab[(size_t)gm * K + gk]) : Af[(size_t)gm * K + gk];
            As[kk][mi] = v;
        }
#pragma unroll
        for (int t = 0; t < 4; ++t) {
            int idx = tid + 256 * t;
            int ni = idx >> 4, kk = idx & 15;
            int gn = n0 + ni, gk = k0 + kk;
            float v = 0.f;
            if (gn < N && gk < K) v = W[(size_t)gn * K + gk];
            Bs[kk][ni] = v;
        }
        __syncthreads();
#pragma unroll
        for (int kk = 0; kk < 16; ++kk) {
            const float4 a4 = *(const float4*)&As[kk][ty * 4];
            const float4 b4 = *(const float4*)&Bs[kk][tx * 4];
            const float ar[4] = {a4.x, a4.y, a4.z, a4.w};
            const float br[4] = {b4.x, b4.y, b4.z, b4.w};
#pragma unroll
            for (int i = 0; i < 4; ++i)
#pragma unroll
                for (int j = 0; j < 4; ++j) acc[i][j] += ar[i] * br[j];
        }
        __syncthreads();
    }
#pragma unroll
    for (int i = 0; i < 4; ++i) {
        int m = m0 + ty * 4 + i;
        if (m >= M) continue;
        size_t orow = (size_t)m;
        if (store_mode == 1) { int mm = m >> 5, bb = m & 31; orow = (size_t)bb * 31 + mm; }
#pragma unroll
        for (int j = 0; j < 4; ++j) {
            int n = n0 + tx * 4 + j;
            if (n >= N) continue;
            float v = acc[i][j] + bias[n];
            if (relu) v = fmaxf(v, 0.f);
            if (c_bf16) ((bf16*)C)[orow * N + n] = f2b(v);
            else        ((float*)C)[orow * N + n] = v;
        }
    }
}

// ---------------------------------------------------------------------------
// MFMA bf16 GEMM: C[M,N] = act(A[M,K]@W[N,K]^T + bias)
// A,W bf16 row-major (both K-contiguous). K % 64 == 0. N % 128 == 0.
// 128x128 tile, BK=64, 4 waves (2x2), each wave 64x64 via 4x4 16x16x32 frags.
// global_load_lds (16B) staging with XOR-swizzled SOURCE (rule #21):
//   LDS unit u of row r holds global unit (u ^ (r&7)); ds_read applies same XOR.
// ---------------------------------------------------------------------------
__global__ __launch_bounds__(256) void mfma_gemm(
    const bf16* __restrict__ A, const bf16* __restrict__ W,
    const float* __restrict__ bias, void* __restrict__ C,
    int M, int N, int K, int c_bf16, int relu, int store_mode)
{
    __shared__ bf16 As[128 * 64];
    __shared__ bf16 Bs[128 * 64];
    const int tid = threadIdx.x;
    const int wave = tid >> 6, lane = tid & 63;
    const int m0 = blockIdx.y * 128, n0 = blockIdx.x * 128;
    const int wr = wave >> 1, wc = wave & 1;
    const int fr = lane & 15, fg = lane >> 4;
    f32x4 acc[4][4] = {};

    const int srow = lane >> 3;                 // row within 8-row chunk
    const int sunit = (lane & 7) ^ srow;        // swizzled 16B source unit

    for (int k0 = 0; k0 < K; k0 += 64) {
#pragma unroll
        for (int c = 0; c < 4; ++c) {
            const int chunk = wave * 4 + c;
            const int arow = m0 + chunk * 8 + srow;
            const int brow = n0 + chunk * 8 + srow;
            gload_lds16(A + (size_t)arow * K + k0 + sunit * 8, (char*)As + chunk * 1024);
            gload_lds16(W + (size_t)brow * K + k0 + sunit * 8, (char*)Bs + chunk * 1024);
        }
        __syncthreads();
#pragma unroll
        for (int kk = 0; kk < 64; kk += 32) {
            bf16x8 af[4], bw[4];
            const int bo = (kk + fg * 8) * 2;   // byte offset of wanted unit
#pragma unroll
            for (int t = 0; t < 4; ++t) {
                const int ra = wr * 64 + t * 16 + fr;
                af[t] = *(const bf16x8*)((const char*)As + ra * 128 + (bo ^ ((ra & 7) << 4)));
                const int rb = wc * 64 + t * 16 + fr;
                bw[t] = *(const bf16x8*)((const char*)Bs + rb * 128 + (bo ^ ((rb & 7) << 4)));
            }
#pragma unroll
            for (int mt = 0; mt < 4; ++mt)
#pragma unroll
                for (int nt = 0; nt < 4; ++nt)
                    acc[mt][nt] = __builtin_amdgcn_mfma_f32_16x16x32_bf16(
                        af[mt], bw[nt], acc[mt][nt], 0, 0, 0);
        }
        __syncthreads();
    }
#pragma unroll
    for (int mt = 0; mt < 4; ++mt) {
#pragma unroll
        for (int r = 0; r < 4; ++r) {
            const int m = m0 + wr * 64 + mt * 16 + fg * 4 + r;
            if (m >= M) continue;
            size_t orow = (size_t)m;
            if (store_mode == 1) orow = (size_t)(m & 31) * 31 + (m >> 5);
#pragma unroll
            for (int nt = 0; nt < 4; ++nt) {
                const int n = n0 + wc * 64 + nt * 16 + fr;
                float v = acc[mt][nt][r] + bias[n];
                if (relu) v = fmaxf(v, 0.f);
                if (c_bf16) ((bf16*)C)[orow * N + n] = f2b(v);
                else        ((float*)C)[orow * N + n] = v;
            }
        }
    }
}

// ---------------------------------------------------------------------------
// Self-attention over qkv (rows = cm*1024, cols 1536: q|k|v), T=32, dh=64.
// ---------------------------------------------------------------------------
__global__ __launch_bounds__(256) void self_attn_kernel(
    const bf16* __restrict__ qkv, const int* __restrict__ input_ids,
    bf16* __restrict__ attn_out, int cm)
{
    const int blk = blockIdx.x;
    const int h = blk & 7;
    const int mb = blk >> 3;
    const int b = mb & 31;
    __shared__ float qs[32][65], ks[32][65], vs[32][65];
    __shared__ int kpm[32];
    const int tid = threadIdx.x;
    const size_t rowbase = (size_t)mb * 32;
    for (int idx = tid; idx < 2048; idx += 256) {
        int r = idx >> 6, c = idx & 63;
        size_t base = (rowbase + r) * 1536;
        qs[r][c] = b2f(qkv[base + h * 64 + c]);
        ks[r][c] = b2f(qkv[base + 512 + h * 64 + c]);
        vs[r][c] = b2f(qkv[base + 1024 + h * 64 + c]);
    }
    if (tid < 32) kpm[tid] = (input_ids[b * 32 + tid] == 0);
    __syncthreads();
    const int lane = tid & 63, wave = tid >> 6;
    const int jj = lane & 31;
    for (int rr = 0; rr < 8; ++rr) {
        int i = wave * 8 + rr;
        float s = 0.f;
#pragma unroll
        for (int d = 0; d < 64; ++d) s += qs[i][d] * ks[jj][d];
        s *= 0.125f;
        if (jj > i) s = -1e9f;
        if (kpm[jj]) s = -1e9f;
        float mx = s;
        for (int o = 16; o; o >>= 1) mx = fmaxf(mx, __shfl_xor(mx, o, 32));
        float e = expf(s - mx);
        float sm = e;
        for (int o = 16; o; o >>= 1) sm += __shfl_xor(sm, o, 32);
        float p = e / sm;
        float acc = 0.f;
#pragma unroll
        for (int j = 0; j < 32; ++j) {
            float pj = __shfl(p, j, 32);
            acc += pj * vs[j][lane];
        }
        attn_out[(rowbase + i) * 512 + h * 64 + lane] = f2b(acc);
    }
}

// ---------------------------------------------------------------------------
// Cross-attention: q rows cm*1024 (512 cols), kv rows cm*864 (1024: k|v), LK=27.
// ---------------------------------------------------------------------------
__global__ __launch_bounds__(256) void cross_attn_kernel(
    const bf16* __restrict__ q, const bf16* __restrict__ kv,
    bf16* __restrict__ attn_out, int cm)
{
    const int blk = blockIdx.x;
    const int h = blk & 7;
    const int mb = blk >> 3;
    __shared__ float qs[32][65], ks[27][65], vs[27][65];
    const int tid = threadIdx.x;
    const size_t qrow = (size_t)mb * 32;
    const size_t kvrow = (size_t)mb * 27;
    for (int idx = tid; idx < 2048; idx += 256) {
        int r = idx >> 6, c = idx & 63;
        qs[r][c] = b2f(q[(qrow + r) * 512 + h * 64 + c]);
    }
    for (int idx = tid; idx < 27 * 64; idx += 256) {
        int r = idx >> 6, c = idx & 63;
        size_t base = (kvrow + r) * 1024;
        ks[r][c] = b2f(kv[base + h * 64 + c]);
        vs[r][c] = b2f(kv[base + 512 + h * 64 + c]);
    }
    __syncthreads();
    const int lane = tid & 63, wave = tid >> 6;
    const int jj = lane & 31;
    for (int rr = 0; rr < 8; ++rr) {
        int i = wave * 8 + rr;
        float s;
        if (jj < 27) {
            s = 0.f;
#pragma unroll
            for (int d = 0; d < 64; ++d) s += qs[i][d] * ks[jj][d];
            s *= 0.125f;
        } else s = -1e30f;
        float mx = s;
        for (int o = 16; o; o >>= 1) mx = fmaxf(mx, __shfl_xor(mx, o, 32));
        float e = expf(s - mx);
        float sm = e;
        for (int o = 16; o; o >>= 1) sm += __shfl_xor(sm, o, 32);
        float p = e / sm;
        float acc = 0.f;
#pragma unroll
        for (int j = 0; j < 27; ++j) {
            float pj = __shfl(p, j, 32);
            acc += pj * vs[j][lane];
        }
        attn_out[(qrow + i) * 512 + h * 64 + lane] = f2b(acc);
    }
}

// ---------------------------------------------------------------------------
// LayerNorm over D=512; optional f32 and bf16 outputs.
// ---------------------------------------------------------------------------
__global__ __launch_bounds__(256) void ln_kernel(
    const float* __restrict__ x, const float* __restrict__ g,
    const float* __restrict__ b_, float* __restrict__ outf,
    bf16* __restrict__ outb, int rows)
{
    int row = blockIdx.x * 4 + (threadIdx.x >> 6);
    if (row >= rows) return;
    int lane = threadIdx.x & 63;
    const float* xr = x + (size_t)row * 512;
    float v[8];
    float sum = 0.f;
#pragma unroll
    for (int k = 0; k < 8; ++k) { v[k] = xr[lane + 64 * k]; sum += v[k]; }
    for (int o = 32; o; o >>= 1) sum += __shfl_xor(sum, o, 64);
    float mean = sum * (1.f / 512.f);
    float vs = 0.f;
#pragma unroll
    for (int k = 0; k < 8; ++k) { float d = v[k] - mean; vs += d * d; }
    for (int o = 32; o; o >>= 1) vs += __shfl_xor(vs, o, 64);
    float rstd = rsqrtf(vs * (1.f / 512.f) + 1e-5f);
#pragma unroll
    for (int k = 0; k < 8; ++k) {
        int c = lane + 64 * k;
        float val = (v[k] - mean) * rstd * g[c] + b_[c];
        if (outf) outf[(size_t)row * 512 + c] = val;
        if (outb) outb[(size_t)row * 512 + c] = f2b(val);
    }
}

// x = LN(x + branch); also writes bf16 copy xb.
__global__ __launch_bounds__(256) void ln_res_kernel(
    float* __restrict__ x, const bf16* __restrict__ br,
    const float* __restrict__ g, const float* __restrict__ b_,
    bf16* __restrict__ xb, int rows)
{
    int row = blockIdx.x * 4 + (threadIdx.x >> 6);
    if (row >= rows) return;
    int lane = threadIdx.x & 63;
    float* xr = x + (size_t)row * 512;
    const bf16* brr = br + (size_t)row * 512;
    float v[8];
    float sum = 0.f;
#pragma unroll
    for (int k = 0; k < 8; ++k) {
        int c = lane + 64 * k;
        v[k] = xr[c] + b2f(brr[c]);
        sum += v[k];
    }
    for (int o = 32; o; o >>= 1) sum += __shfl_xor(sum, o, 64);
    float mean = sum * (1.f / 512.f);
    float vs = 0.f;
#pragma unroll
    for (int k = 0; k < 8; ++k) { float d = v[k] - mean; vs += d * d; }
    for (int o = 32; o; o >>= 1) vs += __shfl_xor(vs, o, 64);
    float rstd = rsqrtf(vs * (1.f / 512.f) + 1e-5f);
#pragma unroll
    for (int k = 0; k < 8; ++k) {
        int c = lane + 64 * k;
        float val = (v[k] - mean) * rstd * g[c] + b_[c];
        xr[c] = val;
        xb[(size_t)row * 512 + c] = f2b(val);
    }
}

// env row build + LN (mem_g/mem_b). rows = 9216.
__global__ __launch_bounds__(256) void env_ln_kernel(
    const float* __restrict__ astate, const int* __restrict__ atok,
    const float* __restrict__ emb, const int* __restrict__ goal,
    const float* __restrict__ g, const float* __restrict__ b_, float* __restrict__ env)
{
    int row = blockIdx.x * 4 + (threadIdx.x >> 6);
    if (row >= 9216) return;
    int lane = threadIdx.x & 63;
    int s9 = row % 9;
    int bt = row / 9;
    float v[8];
    if (s9 < 8) {
        int ar = bt * 8 + s9;
        float msk = (atok[ar] != -1) ? 1.f : 0.f;
#pragma unroll
        for (int k = 0; k < 8; ++k) v[k] = astate[(size_t)ar * 512 + lane + 64 * k] * msk;
    } else {
        int gi = goal[bt >> 5];
#pragma unroll
        for (int k = 0; k < 8; ++k) v[k] = emb[(size_t)gi * 512 + lane + 64 * k];
    }
    float sum = 0.f;
#pragma unroll
    for (int k = 0; k < 8; ++k) sum += v[k];
    for (int o = 32; o; o >>= 1) sum += __shfl_xor(sum, o, 64);
    float mean = sum * (1.f / 512.f);
    float vs = 0.f;
#pragma unroll
    for (int k = 0; k < 8; ++k) { float d = v[k] - mean; vs += d * d; }
    for (int o = 32; o; o >>= 1) vs += __shfl_xor(vs, o, 64);
    float rstd = rsqrtf(vs * (1.f / 512.f) + 1e-5f);
    float* orow = env + (size_t)row * 512;
#pragma unroll
    for (int k = 0; k < 8; ++k) {
        int c = lane + 64 * k;
        orow[c] = (v[k] - mean) * rstd * g[c] + b_[c];
    }
}

// mems gather (bf16)
__global__ void mems_kernel(const float* __restrict__ env, bf16* __restrict__ mems)
{
    int row = blockIdx.x;               // 26784
    int j = row % 27;
    int mb = row / 27;
    int m = mb >> 5, b = mb & 31;
    int gidx = j / 9, sp = j % 9;
    int t = m - 1 + gidx;
    t = t < 0 ? 0 : (t > 31 ? 31 : t);
    const float* src = env + ((size_t)(b * 32 + t) * 9 + sp) * 512;
    bf16* dst = mems + (size_t)row * 512;
    for (int c = threadIdx.x; c < 512; c += 64) dst[c] = f2b(src[c]);
}

__global__ void xcat_kernel(const int* __restrict__ ids, const float* __restrict__ ego,
                            const float* __restrict__ emb, float* __restrict__ xcat)
{
    int row = blockIdx.x;   // 1024
    int b = row >> 5;
    int id = ids[row];
    float* dst = xcat + (size_t)row * 515;
    const float* src = emb + (size_t)id * 512;
    for (int c = threadIdx.x; c < 512; c += 256) dst[c] = src[c];
    if (threadIdx.x < 3) dst[512 + threadIdx.x] = ego[b * 3 + threadIdx.x];
}

__global__ void acat_kernel(const int* __restrict__ atok, const float* __restrict__ afeat,
                            const float* __restrict__ emb, float* __restrict__ acat)
{
    int row = blockIdx.x;   // 8192
    int tok = atok[row];
    int id = (tok != -1) ? tok : 0;
    float* dst = acat + (size_t)row * 517;
    const float* src = emb + (size_t)id * 512;
    for (int c = threadIdx.x; c < 512; c += 256) dst[c] = src[c];
    if (threadIdx.x < 5) dst[512 + threadIdx.x] = afeat[(size_t)row * 5 + threadIdx.x];
}

// broadcast self_state -> x (f32) and xb (bf16)
__global__ void initx_kernel(const float* __restrict__ ss, float* __restrict__ x,
                             bf16* __restrict__ xb, int total)
{
    int i = blockIdx.x * 256 + threadIdx.x;
    if (i < total) {
        float v = ss[i & 524287];
        x[i] = v;
        xb[i] = f2b(v);
    }
}

__global__ void sel_kernel(const float* __restrict__ x, float* __restrict__ sel, int m0, int cm)
{
    int row = blockIdx.x;   // cm*32
    int ml = row >> 5, b = row & 31;
    int m = m0 + ml;
    const float* src = x + ((size_t)(ml * 32 + b) * 32 + (m + 1)) * 512;
    float* dst = sel + ((size_t)m * 32 + b) * 512;
    for (int c = threadIdx.x; c < 512; c += 256) dst[c] = src[c];
}

__global__ void fill_kernel(float* __restrict__ o, int n, float v)
{
    int i = blockIdx.x * 256 + threadIdx.x;
    if (i < n) o[i] = v;
}

// f32 -> bf16 weight conversion (n % 4 == 0), grid-stride on float4s
__global__ void cvtw_kernel(const float* __restrict__ s, unsigned short* __restrict__ d, int n)
{
    int n4 = n >> 2;
    int stride = gridDim.x * blockDim.x;
    for (int i = blockIdx.x * blockDim.x + threadIdx.x; i < n4; i += stride) {
        float4 v = ((const float4*)s)[i];
        ushort4 u;
        u.x = f2bu(v.x); u.y = f2bu(v.y); u.z = f2bu(v.z); u.w = f2bu(v.w);
        ((ushort4*)d)[i] = u;
    }
}

// ---------------------------------------------------------------------------
extern "C" void kernel_launch(void* const* d_in, const int* in_sizes, int n_in,
                              void* d_out, int out_size, void* d_ws, size_t ws_size,
                              hipStream_t stream)
{
    float* out = (float*)d_out;
    if (n_in < 40) {
        fill_kernel<<<(out_size + 255) / 256, 256, 0, stream>>>(out, out_size, 1e6f);
        return;
    }
    const int*   input_ids = (const int*)d_in[0];
    const float* ego       = (const float*)d_in[1];
    const int*   atok      = (const int*)d_in[2];
    const float* afeat     = (const float*)d_in[3];
    const int*   goal      = (const int*)d_in[4];
    const float* emb       = (const float*)d_in[5];
    const float* se_w1 = (const float*)d_in[6];
    const float* se_b1 = (const float*)d_in[7];
    const float* se_w2 = (const float*)d_in[8];
    const float* se_b2 = (const float*)d_in[9];
    const float* be_w1 = (const float*)d_in[10];
    const float* be_b1 = (const float*)d_in[11];
    const float* be_w2 = (const float*)d_in[12];
    const float* be_b2 = (const float*)d_in[13];
    const float* in_g  = (const float*)d_in[14];
    const float* in_b  = (const float*)d_in[15];
    const float* mem_g = (const float*)d_in[16];
    const float* mem_b = (const float*)d_in[17];
    const float* outn_g = (const float*)d_in[18];
    const float* outn_b = (const float*)d_in[19];
    const float* sa_in_w  = (const float*)d_in[20];
    const float* sa_in_b  = (const float*)d_in[21];
    const float* sa_out_w = (const float*)d_in[22];
    const float* sa_out_b = (const float*)d_in[23];
    const float* ca_in_w  = (const float*)d_in[24];
    const float* ca_in_b  = (const float*)d_in[25];
    const float* ca_out_w = (const float*)d_in[26];
    const float* ca_out_b = (const float*)d_in[27];
    const float* ff_w1 = (const float*)d_in[28];
    const float* ff_b1 = (const float*)d_in[29];
    const float* ff_w2 = (const float*)d_in[30];
    const float* ff_b2 = (const float*)d_in[31];
    const float* ln1_g = (const float*)d_in[32];
    const float* ln1_b = (const float*)d_in[33];
    const float* ln2_g = (const float*)d_in[34];
    const float* ln2_b = (const float*)d_in[35];
    const float* ln3_g = (const float*)d_in[36];
    const float* ln3_b = (const float*)d_in[37];
    const float* proj_w = (const float*)d_in[38];
    const float* proj_b = (const float*)d_in[39];

    auto ALIGN = [](size_t b) { return (b + 255) & ~(size_t)255; };
    uintptr_t base = (uintptr_t)d_ws;
    uintptr_t cur = (base + 255) & ~(uintptr_t)255;
    auto alloc = [&](size_t bytes) -> char* {
        char* r = (char*)cur; cur += (bytes + 255) & ~(size_t)255; return r;
    };

    // ---------------- persistent allocations ----------------
    float* self_state = (float*)alloc((size_t)1024 * 512 * 4);
    bf16*  mems       = (bf16*) alloc((size_t)(26784 + 128) * 512 * 2);
    float* sel        = (float*)alloc((size_t)1024 * 512 * 4);
    bf16*  sel_ln_b   = (bf16*) alloc((size_t)1024 * 512 * 2);
    // bf16 weight arena
    bf16* w_se2   = (bf16*)alloc((size_t)512 * 512 * 2);
    bf16* w_be2   = (bf16*)alloc((size_t)512 * 512 * 2);
    bf16* w_sain  = (bf16*)alloc((size_t)4 * 1536 * 512 * 2);
    bf16* w_saout = (bf16*)alloc((size_t)4 * 512 * 512 * 2);
    bf16* w_cain  = (bf16*)alloc((size_t)4 * 1536 * 512 * 2);
    bf16* w_caout = (bf16*)alloc((size_t)4 * 512 * 512 * 2);
    bf16* w_ff1   = (bf16*)alloc((size_t)4 * 2048 * 512 * 2);
    bf16* w_ff2   = (bf16*)alloc((size_t)4 * 2048 * 512 * 2);
    bf16* w_proj  = (bf16*)alloc((size_t)4096 * 512 * 2);
    uintptr_t big = cur;

    size_t setup_need =
        ALIGN((size_t)1024 * 515 * 4) + ALIGN((size_t)1024 * 512 * 2) + ALIGN((size_t)1024 * 512 * 4) +
        ALIGN((size_t)8192 * 517 * 4) + ALIGN((size_t)8192 * 512 * 2) + ALIGN((size_t)8192 * 512 * 4) +
        ALIGN((size_t)9216 * 512 * 4);
    auto chunk_need = [&](int c) -> size_t {
        return ALIGN((size_t)c * 1024 * 512 * 4)          // x f32
             + ALIGN((size_t)c * 1024 * 512 * 2)          // xb bf16
             + ALIGN((size_t)c * 1024 * 1536 * 2)         // qkv
             + ALIGN((size_t)c * 1024 * 512 * 2)          // araw
             + ALIGN((size_t)c * 1024 * 512 * 2)          // brnch
             + ALIGN((size_t)c * 1024 * 2048 * 2)         // ff1
             + ALIGN(((size_t)c * 864 + 128) * 1024 * 2); // kv (+pad)
    };
    int CH = 0;
    if (ws_size > (size_t)(big - base) + 4096) {
        size_t avail = ws_size - (size_t)(big - base) - 4096;
        for (int c = 31; c >= 1; --c)
            if (setup_need <= avail && chunk_need(c) <= avail) { CH = c; break; }
    }
    if (!CH) {
        fill_kernel<<<(out_size + 255) / 256, 256, 0, stream>>>(out, out_size, 1e6f);
        return;
    }

    // ---------------- weight conversion ----------------
    auto cvt = [&](const float* s, bf16* d, size_t n) {
        int n4 = (int)(n >> 2);
        int blocks = (n4 + 255) / 256; if (blocks > 2048) blocks = 2048;
        cvtw_kernel<<<blocks, 256, 0, stream>>>(s, (unsigned short*)d, (int)n);
    };
    cvt(se_w2, w_se2, (size_t)512 * 512);
    cvt(be_w2, w_be2, (size_t)512 * 512);
    cvt(sa_in_w, w_sain, (size_t)4 * 1536 * 512);
    cvt(sa_out_w, w_saout, (size_t)4 * 512 * 512);
    cvt(ca_in_w, w_cain, (size_t)4 * 1536 * 512);
    cvt(ca_out_w, w_caout, (size_t)4 * 512 * 512);
    cvt(ff_w1, w_ff1, (size_t)4 * 2048 * 512);
    cvt(ff_w2, w_ff2, (size_t)4 * 2048 * 512);
    cvt(proj_w, w_proj, (size_t)4096 * 512);

    auto launch_f32gemm = [&](const void* A, int a_bf16, const float* W, const float* bias,
                              void* C, int c_bf16, int M, int N, int K, int relu) {
        dim3 g((N + 63) / 64, (M + 63) / 64);
        gemm_kernel<<<g, 256, 0, stream>>>(A, W, bias, C, M, N, K, a_bf16, c_bf16, relu, 0);
    };
    auto launch_mfma = [&](const bf16* A, const bf16* W, const float* bias,
                           void* C, int c_bf16, int M, int N, int K, int relu, int smode) {
        dim3 g(N / 128, (M + 127) / 128);
        mfma_gemm<<<g, 256, 0, stream>>>(A, W, bias, C, M, N, K, c_bf16, relu, smode);
    };

    // ---------------- setup: encoders, env, mems ----------------
    {
        uintptr_t sp = big;
        auto salloc = [&](size_t b) -> char* { char* r = (char*)sp; sp += ALIGN(b); return r; };
        float* xcat   = (float*)salloc((size_t)1024 * 515 * 4);
        bf16*  h1b    = (bf16*) salloc((size_t)1024 * 512 * 2);
        float* fused  = (float*)salloc((size_t)1024 * 512 * 4);
        float* acat   = (float*)salloc((size_t)8192 * 517 * 4);
        bf16*  ah1b   = (bf16*) salloc((size_t)8192 * 512 * 2);
        float* astate = (float*)salloc((size_t)8192 * 512 * 4);
        float* env    = (float*)salloc((size_t)9216 * 512 * 4);

        xcat_kernel<<<1024, 256, 0, stream>>>(input_ids, ego, emb, xcat);
        launch_f32gemm(xcat, 0, se_w1, se_b1, h1b, 1, 1024, 512, 515, 1);
        launch_mfma(h1b, w_se2, se_b2, fused, 0, 1024, 512, 512, 0, 0);
        ln_kernel<<<256, 256, 0, stream>>>(fused, in_g, in_b, self_state, (bf16*)nullptr, 1024);

        acat_kernel<<<8192, 256, 0, stream>>>(atok, afeat, emb, acat);
        launch_f32gemm(acat, 0, be_w1, be_b1, ah1b, 1, 8192, 512, 517, 1);
        launch_mfma(ah1b, w_be2, be_b2, astate, 0, 8192, 512, 512, 0, 0);
        env_ln_kernel<<<2304, 256, 0, stream>>>(astate, atok, emb, goal, mem_g, mem_b, env);
        mems_kernel<<<26784, 64, 0, stream>>>(env, mems);
    }

    // ---------------- decode ----------------
    {
        uintptr_t sp = big;
        auto salloc = [&](size_t b) -> char* { char* r = (char*)sp; sp += ALIGN(b); return r; };
        float* x     = (float*)salloc((size_t)CH * 1024 * 512 * 4);
        bf16*  xb    = (bf16*) salloc((size_t)CH * 1024 * 512 * 2);
        bf16*  qkv   = (bf16*) salloc((size_t)CH * 1024 * 1536 * 2);
        bf16*  araw  = (bf16*) salloc((size_t)CH * 1024 * 512 * 2);
        bf16*  brnch = (bf16*) salloc((size_t)CH * 1024 * 512 * 2);
        bf16*  ff1b  = (bf16*) salloc((size_t)CH * 1024 * 2048 * 2);
        bf16*  kv    = (bf16*) salloc(((size_t)CH * 864 + 128) * 1024 * 2);

        for (int m0 = 0; m0 < 31; m0 += CH) {
            int cm = (31 - m0) < CH ? (31 - m0) : CH;
            int Mr = cm * 1024;
            initx_kernel<<<cm * 2048, 256, 0, stream>>>(self_state, x, xb, Mr * 512);
            for (int l = 0; l < 4; ++l) {
                // --- self attention ---
                launch_mfma(xb, w_sain + (size_t)l * 1536 * 512, sa_in_b + l * 1536,
                            qkv, 1, Mr, 1536, 512, 0, 0);
                self_attn_kernel<<<cm * 32 * 8, 256, 0, stream>>>(qkv, input_ids, araw, cm);
                launch_mfma(araw, w_saout + (size_t)l * 512 * 512, sa_out_b + l * 512,
                            brnch, 1, Mr, 512, 512, 0, 0);
                ln_res_kernel<<<(Mr + 3) / 4, 256, 0, stream>>>(x, brnch, ln1_g + l * 512, ln1_b + l * 512, xb, Mr);
                // --- cross attention ---
                launch_mfma(xb, w_cain + (size_t)l * 1536 * 512, ca_in_b + l * 1536,
                            qkv, 1, Mr, 512, 512, 0, 0);                               // q only (N=512)
                launch_mfma(mems + (size_t)m0 * 864 * 512,
                            w_cain + (size_t)l * 1536 * 512 + (size_t)512 * 512,
                            ca_in_b + l * 1536 + 512,
                            kv, 1, cm * 864, 1024, 512, 0, 0);                         // k|v
                cross_attn_kernel<<<cm * 32 * 8, 256, 0, stream>>>(qkv, kv, araw, cm);
                launch_mfma(araw, w_caout + (size_t)l * 512 * 512, ca_out_b + l * 512,
                            brnch, 1, Mr, 512, 512, 0, 0);
                ln_res_kernel<<<(Mr + 3) / 4, 256, 0, stream>>>(x, brnch, ln2_g + l * 512, ln2_b + l * 512, xb, Mr);
                // --- FFN ---
                launch_mfma(xb, w_ff1 + (size_t)l * 2048 * 512, ff_b1 + l * 2048,
                            ff1b, 1, Mr, 2048, 512, 1, 0);
                launch_mfma(ff1b, w_ff2 + (size_t)l * 512 * 2048, ff_b2 + l * 512,
                            brnch, 1, Mr, 512, 2048, 0, 0);
                ln_res_kernel<<<(Mr + 3) / 4, 256, 0, stream>>>(x, brnch, ln3_g + l * 512, ln3_b + l * 512, xb, Mr);
            }
            sel_kernel<<<cm * 32, 256, 0, stream>>>(x, sel, m0, cm);
        }
    }

    // ---------------- final: LN + vocab projection (transposed store) ----------------
    ln_kernel<<<248, 256, 0, stream>>>(sel, outn_g, outn_b, (float*)nullptr, sel_ln_b, 992);
    launch_mfma(sel_ln_b, w_proj, proj_b, out, 0, 992, 4096, 512, 0, 1);
}

// Round 3
// 5386.718 us; speedup vs baseline: 3.7766x; 1.0513x over previous
//
#include <hip/hip_runtime.h>
#include <hip/hip_bf16.h>
#include <stdint.h>

typedef __hip_bfloat16 bf16;
typedef __attribute__((ext_vector_type(8))) short bf16x8;
typedef __attribute__((ext_vector_type(4))) float f32x4;

__device__ __forceinline__ float b2f(bf16 v) { return __bfloat162float(v); }
__device__ __forceinline__ bf16 f2b(float v) { return __float2bfloat16(v); }
__device__ __forceinline__ unsigned short f2bu(float v) {
    bf16 h = __float2bfloat16(v);
    return *(unsigned short*)&h;
}
__device__ __forceinline__ float su2f(unsigned short u) {
    unsigned int x = ((unsigned int)u) << 16;
    return *(float*)&x;
}

__device__ __forceinline__ void gload_lds16(const void* g, void* l) {
    __builtin_amdgcn_global_load_lds((const __attribute__((address_space(1))) void*)g,
                                     (__attribute__((address_space(3))) void*)l, 16, 0, 0);
}

// ---------------------------------------------------------------------------
// MFMA bf16 GEMM: C[M,N] = act(A[M,K]@W[N,K]^T + bias)
// A,W bf16 row-major (K-contig). K%64==0, N%128==0. M padded to 128 (stores guarded).
// 128x128 tile, BK=64, 4 waves (2x2), 4x4 16x16x32 frags per wave.
// global_load_lds 16B staging, XOR-swizzled SOURCE + swizzled ds_read (rule #21).
// ---------------------------------------------------------------------------
__global__ __launch_bounds__(256) void mfma_gemm(
    const bf16* __restrict__ A, const bf16* __restrict__ W,
    const float* __restrict__ bias, void* __restrict__ C,
    int M, int N, int K, int c_bf16, int relu, int store_mode)
{
    __shared__ bf16 As[128 * 64];
    __shared__ bf16 Bs[128 * 64];
    const int tid = threadIdx.x;
    const int wave = tid >> 6, lane = tid & 63;
    const int m0 = blockIdx.y * 128, n0 = blockIdx.x * 128;
    const int wr = wave >> 1, wc = wave & 1;
    const int fr = lane & 15, fg = lane >> 4;
    f32x4 acc[4][4] = {};

    const int srow = lane >> 3;
    const int sunit = (lane & 7) ^ srow;

    for (int k0 = 0; k0 < K; k0 += 64) {
#pragma unroll
        for (int c = 0; c < 4; ++c) {
            const int chunk = wave * 4 + c;
            const int arow = m0 + chunk * 8 + srow;
            const int brow = n0 + chunk * 8 + srow;
            gload_lds16(A + (size_t)arow * K + k0 + sunit * 8, (char*)As + chunk * 1024);
            gload_lds16(W + (size_t)brow * K + k0 + sunit * 8, (char*)Bs + chunk * 1024);
        }
        __syncthreads();
#pragma unroll
        for (int kk = 0; kk < 64; kk += 32) {
            bf16x8 af[4], bw[4];
            const int bo = (kk + fg * 8) * 2;
#pragma unroll
            for (int t = 0; t < 4; ++t) {
                const int ra = wr * 64 + t * 16 + fr;
                af[t] = *(const bf16x8*)((const char*)As + ra * 128 + (bo ^ ((ra & 7) << 4)));
                const int rb = wc * 64 + t * 16 + fr;
                bw[t] = *(const bf16x8*)((const char*)Bs + rb * 128 + (bo ^ ((rb & 7) << 4)));
            }
#pragma unroll
            for (int mt = 0; mt < 4; ++mt)
#pragma unroll
                for (int nt = 0; nt < 4; ++nt)
                    acc[mt][nt] = __builtin_amdgcn_mfma_f32_16x16x32_bf16(
                        af[mt], bw[nt], acc[mt][nt], 0, 0, 0);
        }
        __syncthreads();
    }
#pragma unroll
    for (int mt = 0; mt < 4; ++mt) {
#pragma unroll
        for (int r = 0; r < 4; ++r) {
            const int m = m0 + wr * 64 + mt * 16 + fg * 4 + r;
            if (m >= M) continue;
            size_t orow = (size_t)m;
            if (store_mode == 1) orow = (size_t)(m & 31) * 31 + (m >> 5);
#pragma unroll
            for (int nt = 0; nt < 4; ++nt) {
                const int n = n0 + wc * 64 + nt * 16 + fr;
                float v = acc[mt][nt][r] + bias[n];
                if (relu) v = fmaxf(v, 0.f);
                if (c_bf16) ((bf16*)C)[orow * N + n] = f2b(v);
                else        ((float*)C)[orow * N + n] = v;
            }
        }
    }
}

// ---------------------------------------------------------------------------
// Self-attention: qkv rows = cm*1024 (cols 1536: q|k|v), T=32, dh=64.
// One block (4 waves) per (mb, head). Vectorized bf16x8 staging.
// ---------------------------------------------------------------------------
__global__ __launch_bounds__(256) void self_attn_kernel(
    const bf16* __restrict__ qkv, const int* __restrict__ input_ids,
    bf16* __restrict__ attn_out, int cm)
{
    const int blk = blockIdx.x;
    const int h = blk & 7;
    const int mb = blk >> 3;
    const int b = mb & 31;
    __shared__ float qs[32][65], ks[32][65], vs[32][65];
    __shared__ int kpm[32];
    const int tid = threadIdx.x;
    const size_t rowbase = (size_t)mb * 32;
    {
        int r = tid >> 3, u = tid & 7;
        size_t base = (rowbase + r) * 1536 + h * 64 + u * 8;
        bf16x8 q8 = *(const bf16x8*)(qkv + base);
        bf16x8 k8 = *(const bf16x8*)(qkv + base + 512);
        bf16x8 v8 = *(const bf16x8*)(qkv + base + 1024);
#pragma unroll
        for (int e = 0; e < 8; ++e) {
            qs[r][u * 8 + e] = su2f((unsigned short)q8[e]);
            ks[r][u * 8 + e] = su2f((unsigned short)k8[e]);
            vs[r][u * 8 + e] = su2f((unsigned short)v8[e]);
        }
    }
    if (tid < 32) kpm[tid] = (input_ids[b * 32 + tid] == 0);
    __syncthreads();
    const int lane = tid & 63, wave = tid >> 6;
    const int jj = lane & 31;
    for (int rr = 0; rr < 8; ++rr) {
        int i = wave * 8 + rr;
        float s = 0.f;
#pragma unroll
        for (int d = 0; d < 64; ++d) s += qs[i][d] * ks[jj][d];
        s *= 0.125f;
        if (jj > i) s = -1e9f;
        if (kpm[jj]) s = -1e9f;
        float mx = s;
        for (int o = 16; o; o >>= 1) mx = fmaxf(mx, __shfl_xor(mx, o, 32));
        float e = expf(s - mx);
        float sm = e;
        for (int o = 16; o; o >>= 1) sm += __shfl_xor(sm, o, 32);
        float p = e / sm;
        float acc = 0.f;
#pragma unroll
        for (int j = 0; j < 32; ++j) {
            float pj = __shfl(p, j, 32);
            acc += pj * vs[j][lane];
        }
        attn_out[(rowbase + i) * 512 + h * 64 + lane] = f2b(acc);
    }
}

// ---------------------------------------------------------------------------
// Cross-attention: q rows cm*1024 (512 cols), kv rows cm*864 (1024: k|v), LK=27.
// ---------------------------------------------------------------------------
__global__ __launch_bounds__(256) void cross_attn_kernel(
    const bf16* __restrict__ q, const bf16* __restrict__ kv,
    bf16* __restrict__ attn_out, int cm)
{
    const int blk = blockIdx.x;
    const int h = blk & 7;
    const int mb = blk >> 3;
    __shared__ float qs[32][65], ks[27][65], vs[27][65];
    const int tid = threadIdx.x;
    const size_t qrow = (size_t)mb * 32;
    const size_t kvrow = (size_t)mb * 27;
    {
        int r = tid >> 3, u = tid & 7;
        bf16x8 q8 = *(const bf16x8*)(q + (qrow + r) * 512 + h * 64 + u * 8);
#pragma unroll
        for (int e = 0; e < 8; ++e) qs[r][u * 8 + e] = su2f((unsigned short)q8[e]);
    }
    if (tid < 216) {
        int r = tid >> 3, u = tid & 7;
        size_t base = (kvrow + r) * 1024 + h * 64 + u * 8;
        bf16x8 k8 = *(const bf16x8*)(kv + base);
        bf16x8 v8 = *(const bf16x8*)(kv + base + 512);
#pragma unroll
        for (int e = 0; e < 8; ++e) {
            ks[r][u * 8 + e] = su2f((unsigned short)k8[e]);
            vs[r][u * 8 + e] = su2f((unsigned short)v8[e]);
        }
    }
    __syncthreads();
    const int lane = tid & 63, wave = tid >> 6;
    const int jj = lane & 31;
    for (int rr = 0; rr < 8; ++rr) {
        int i = wave * 8 + rr;
        float s;
        if (jj < 27) {
            s = 0.f;
#pragma unroll
            for (int d = 0; d < 64; ++d) s += qs[i][d] * ks[jj][d];
            s *= 0.125f;
        } else s = -1e30f;
        float mx = s;
        for (int o = 16; o; o >>= 1) mx = fmaxf(mx, __shfl_xor(mx, o, 32));
        float e = expf(s - mx);
        float sm = e;
        for (int o = 16; o; o >>= 1) sm += __shfl_xor(sm, o, 32);
        float p = e / sm;
        float acc = 0.f;
#pragma unroll
        for (int j = 0; j < 27; ++j) {
            float pj = __shfl(p, j, 32);
            acc += pj * vs[j][lane];
        }
        attn_out[(qrow + i) * 512 + h * 64 + lane] = f2b(acc);
    }
}

// ---------------------------------------------------------------------------
// LayerNorm over D=512, vectorized float4. Optional f32 / bf16 outputs.
// ---------------------------------------------------------------------------
__global__ __launch_bounds__(256) void ln_kernel(
    const float* __restrict__ x, const float* __restrict__ g,
    const float* __restrict__ b_, float* __restrict__ outf,
    bf16* __restrict__ outb, int rows)
{
    int row = blockIdx.x * 4 + (threadIdx.x >> 6);
    if (row >= rows) return;
    int lane = threadIdx.x & 63;
    const float4* xr = (const float4*)(x + (size_t)row * 512);
    float4 v[2];
    float sum = 0.f;
#pragma unroll
    for (int j = 0; j < 2; ++j) {
        v[j] = xr[lane + 64 * j];
        sum += v[j].x + v[j].y + v[j].z + v[j].w;
    }
    for (int o = 32; o; o >>= 1) sum += __shfl_xor(sum, o, 64);
    float mean = sum * (1.f / 512.f);
    float vs = 0.f;
#pragma unroll
    for (int j = 0; j < 2; ++j) {
        float dx = v[j].x - mean, dy = v[j].y - mean, dz = v[j].z - mean, dw = v[j].w - mean;
        vs += dx * dx + dy * dy + dz * dz + dw * dw;
    }
    for (int o = 32; o; o >>= 1) vs += __shfl_xor(vs, o, 64);
    float rstd = rsqrtf(vs * (1.f / 512.f) + 1e-5f);
#pragma unroll
    for (int j = 0; j < 2; ++j) {
        int u = lane + 64 * j;
        float4 g4 = ((const float4*)g)[u];
        float4 b4 = ((const float4*)b_)[u];
        float4 o4;
        o4.x = (v[j].x - mean) * rstd * g4.x + b4.x;
        o4.y = (v[j].y - mean) * rstd * g4.y + b4.y;
        o4.z = (v[j].z - mean) * rstd * g4.z + b4.z;
        o4.w = (v[j].w - mean) * rstd * g4.w + b4.w;
        if (outf) ((float4*)(outf + (size_t)row * 512))[u] = o4;
        if (outb) {
            ushort4 s4 = { f2bu(o4.x), f2bu(o4.y), f2bu(o4.z), f2bu(o4.w) };
            ((ushort4*)(outb + (size_t)row * 512))[u] = s4;
        }
    }
}

// x = LN(x + branch); writes f32 x and bf16 xb. Vectorized.
__global__ __launch_bounds__(256) void ln_res_kernel(
    float* __restrict__ x, const bf16* __restrict__ br,
    const float* __restrict__ g, const float* __restrict__ b_,
    bf16* __restrict__ xb, int rows)
{
    int row = blockIdx.x * 4 + (threadIdx.x >> 6);
    if (row >= rows) return;
    int lane = threadIdx.x & 63;
    float4* xr = (float4*)(x + (size_t)row * 512);
    const ushort4* brr = (const ushort4*)(br + (size_t)row * 512);
    float4 v[2];
    float sum = 0.f;
#pragma unroll
    for (int j = 0; j < 2; ++j) {
        int u = lane + 64 * j;
        float4 a = xr[u];
        ushort4 s4 = brr[u];
        a.x += su2f(s4.x); a.y += su2f(s4.y); a.z += su2f(s4.z); a.w += su2f(s4.w);
        v[j] = a;
        sum += a.x + a.y + a.z + a.w;
    }
    for (int o = 32; o; o >>= 1) sum += __shfl_xor(sum, o, 64);
    float mean = sum * (1.f / 512.f);
    float vs = 0.f;
#pragma unroll
    for (int j = 0; j < 2; ++j) {
        float dx = v[j].x - mean, dy = v[j].y - mean, dz = v[j].z - mean, dw = v[j].w - mean;
        vs += dx * dx + dy * dy + dz * dz + dw * dw;
    }
    for (int o = 32; o; o >>= 1) vs += __shfl_xor(vs, o, 64);
    float rstd = rsqrtf(vs * (1.f / 512.f) + 1e-5f);
#pragma unroll
    for (int j = 0; j < 2; ++j) {
        int u = lane + 64 * j;
        float4 g4 = ((const float4*)g)[u];
        float4 b4 = ((const float4*)b_)[u];
        float4 o4;
        o4.x = (v[j].x - mean) * rstd * g4.x + b4.x;
        o4.y = (v[j].y - mean) * rstd * g4.y + b4.y;
        o4.z = (v[j].z - mean) * rstd * g4.z + b4.z;
        o4.w = (v[j].w - mean) * rstd * g4.w + b4.w;
        xr[u] = o4;
        ushort4 s4 = { f2bu(o4.x), f2bu(o4.y), f2bu(o4.z), f2bu(o4.w) };
        ((ushort4*)(xb + (size_t)row * 512))[u] = s4;
    }
}

// env row build + LN (mem_g/mem_b). rows = 9216.
__global__ __launch_bounds__(256) void env_ln_kernel(
    const float* __restrict__ astate, const int* __restrict__ atok,
    const float* __restrict__ emb, const int* __restrict__ goal,
    const float* __restrict__ g, const float* __restrict__ b_, float* __restrict__ env)
{
    int row = blockIdx.x * 4 + (threadIdx.x >> 6);
    if (row >= 9216) return;
    int lane = threadIdx.x & 63;
    int s9 = row % 9;
    int bt = row / 9;
    float4 v[2];
    if (s9 < 8) {
        int ar = bt * 8 + s9;
        float msk = (atok[ar] != -1) ? 1.f : 0.f;
#pragma unroll
        for (int j = 0; j < 2; ++j) {
            float4 a = ((const float4*)(astate + (size_t)ar * 512))[lane + 64 * j];
            a.x *= msk; a.y *= msk; a.z *= msk; a.w *= msk;
            v[j] = a;
        }
    } else {
        int gi = goal[bt >> 5];
#pragma unroll
        for (int j = 0; j < 2; ++j)
            v[j] = ((const float4*)(emb + (size_t)gi * 512))[lane + 64 * j];
    }
    float sum = 0.f;
#pragma unroll
    for (int j = 0; j < 2; ++j) sum += v[j].x + v[j].y + v[j].z + v[j].w;
    for (int o = 32; o; o >>= 1) sum += __shfl_xor(sum, o, 64);
    float mean = sum * (1.f / 512.f);
    float vs = 0.f;
#pragma unroll
    for (int j = 0; j < 2; ++j) {
        float dx = v[j].x - mean, dy = v[j].y - mean, dz = v[j].z - mean, dw = v[j].w - mean;
        vs += dx * dx + dy * dy + dz * dz + dw * dw;
    }
    for (int o = 32; o; o >>= 1) vs += __shfl_xor(vs, o, 64);
    float rstd = rsqrtf(vs * (1.f / 512.f) + 1e-5f);
#pragma unroll
    for (int j = 0; j < 2; ++j) {
        int u = lane + 64 * j;
        float4 g4 = ((const float4*)g)[u];
        float4 b4 = ((const float4*)b_)[u];
        float4 o4;
        o4.x = (v[j].x - mean) * rstd * g4.x + b4.x;
        o4.y = (v[j].y - mean) * rstd * g4.y + b4.y;
        o4.z = (v[j].z - mean) * rstd * g4.z + b4.z;
        o4.w = (v[j].w - mean) * rstd * g4.w + b4.w;
        ((float4*)(env + (size_t)row * 512))[u] = o4;
    }
}

// mems gather (bf16), vectorized
__global__ void mems_kernel(const float* __restrict__ env, bf16* __restrict__ mems)
{
    int row = blockIdx.x;               // 26784
    int j = row % 27;
    int mb = row / 27;
    int m = mb >> 5, b = mb & 31;
    int gidx = j / 9, sp = j % 9;
    int t = m - 1 + gidx;
    t = t < 0 ? 0 : (t > 31 ? 31 : t);
    const float4* src = (const float4*)(env + ((size_t)(b * 32 + t) * 9 + sp) * 512);
    ushort4* dst = (ushort4*)(mems + (size_t)row * 512);
    int tid = threadIdx.x;
#pragma unroll
    for (int k = 0; k < 2; ++k) {
        int u = tid + 64 * k;
        float4 a = src[u];
        ushort4 s4 = { f2bu(a.x), f2bu(a.y), f2bu(a.z), f2bu(a.w) };
        dst[u] = s4;
    }
}

// xcat_b (bf16 [1024][576]): emb_b row | ego(3) | zeros
__global__ void xcatb_kernel(const int* __restrict__ ids, const float* __restrict__ ego,
                             const bf16* __restrict__ emb_b, bf16* __restrict__ xcat)
{
    int row = blockIdx.x;   // 1024
    int tid = threadIdx.x;  // 128
    int b = row >> 5;
    int id = ids[row];
    bf16x8* dst = (bf16x8*)(xcat + (size_t)row * 576);
    if (tid < 64) {
        dst[tid] = ((const bf16x8*)(emb_b + (size_t)id * 512))[tid];
    } else if (tid == 64) {
        bf16x8 u = {};
        u[0] = (short)f2bu(ego[b * 3 + 0]);
        u[1] = (short)f2bu(ego[b * 3 + 1]);
        u[2] = (short)f2bu(ego[b * 3 + 2]);
        dst[64] = u;
    } else if (tid < 72) {
        bf16x8 z = {};
        dst[tid] = z;
    }
}

// acat_b (bf16 [8192][576]): emb_b[masked tok] | afeat(5) | zeros
__global__ void acatb_kernel(const int* __restrict__ atok, const float* __restrict__ afeat,
                             const bf16* __restrict__ emb_b, bf16* __restrict__ acat)
{
    int row = blockIdx.x;   // 8192
    int tid = threadIdx.x;  // 128
    int tok = atok[row];
    int id = (tok != -1) ? tok : 0;
    bf16x8* dst = (bf16x8*)(acat + (size_t)row * 576);
    if (tid < 64) {
        dst[tid] = ((const bf16x8*)(emb_b + (size_t)id * 512))[tid];
    } else if (tid == 64) {
        bf16x8 u = {};
#pragma unroll
        for (int e = 0; e < 5; ++e) u[e] = (short)f2bu(afeat[(size_t)row * 5 + e]);
        dst[64] = u;
    } else if (tid < 72) {
        bf16x8 z = {};
        dst[tid] = z;
    }
}

// broadcast self_state -> x (f32) and xb (bf16), vectorized (total4 = elems/4)
__global__ void initx_kernel(const float* __restrict__ ss, float* __restrict__ x,
                             bf16* __restrict__ xb, int total4)
{
    int i = blockIdx.x * 256 + threadIdx.x;
    if (i < total4) {
        float4 a = ((const float4*)ss)[i & 131071];
        ((float4*)x)[i] = a;
        ushort4 s4 = { f2bu(a.x), f2bu(a.y), f2bu(a.z), f2bu(a.w) };
        ((ushort4*)xb)[i] = s4;
    }
}

__global__ void sel_kernel(const float* __restrict__ x, float* __restrict__ sel, int m0, int cm)
{
    int row = blockIdx.x;   // cm*32
    int ml = row >> 5, b = row & 31;
    int m = m0 + ml;
    const float4* src = (const float4*)(x + ((size_t)(ml * 32 + b) * 32 + (m + 1)) * 512);
    float4* dst = (float4*)(sel + ((size_t)m * 32 + b) * 512);
    int tid = threadIdx.x;  // 128
    dst[tid] = src[tid];
}

__global__ void fill_kernel(float* __restrict__ o, int n, float v)
{
    int i = blockIdx.x * 256 + threadIdx.x;
    if (i < n) o[i] = v;
}

// f32 -> bf16 (n % 4 == 0), grid-stride on float4s
__global__ void cvtw_kernel(const float* __restrict__ s, unsigned short* __restrict__ d, int n)
{
    int n4 = n >> 2;
    int stride = gridDim.x * blockDim.x;
    for (int i = blockIdx.x * blockDim.x + threadIdx.x; i < n4; i += stride) {
        float4 v = ((const float4*)s)[i];
        ushort4 u = { f2bu(v.x), f2bu(v.y), f2bu(v.z), f2bu(v.w) };
        ((ushort4*)d)[i] = u;
    }
}

// f32 [N][Ks] -> bf16 [N][576] zero-padded
__global__ void cvtpad_kernel(const float* __restrict__ s, bf16* __restrict__ d, int Ks)
{
    int row = blockIdx.x;   // N rows
    int tid = threadIdx.x;  // 256
    for (int c = tid; c < 576; c += 256) {
        float v = (c < Ks) ? s[(size_t)row * Ks + c] : 0.f;
        d[(size_t)row * 576 + c] = f2b(v);
    }
}

// ---------------------------------------------------------------------------
extern "C" void kernel_launch(void* const* d_in, const int* in_sizes, int n_in,
                              void* d_out, int out_size, void* d_ws, size_t ws_size,
                              hipStream_t stream)
{
    float* out = (float*)d_out;
    if (n_in < 40) {
        fill_kernel<<<(out_size + 255) / 256, 256, 0, stream>>>(out, out_size, 1e6f);
        return;
    }
    const int*   input_ids = (const int*)d_in[0];
    const float* ego       = (const float*)d_in[1];
    const int*   atok      = (const int*)d_in[2];
    const float* afeat     = (const float*)d_in[3];
    const int*   goal      = (const int*)d_in[4];
    const float* emb       = (const float*)d_in[5];
    const float* se_w1 = (const float*)d_in[6];
    const float* se_b1 = (const float*)d_in[7];
    const float* se_w2 = (const float*)d_in[8];
    const float* se_b2 = (const float*)d_in[9];
    const float* be_w1 = (const float*)d_in[10];
    const float* be_b1 = (const float*)d_in[11];
    const float* be_w2 = (const float*)d_in[12];
    const float* be_b2 = (const float*)d_in[13];
    const float* in_g  = (const float*)d_in[14];
    const float* in_b  = (const float*)d_in[15];
    const float* mem_g = (const float*)d_in[16];
    const float* mem_b = (const float*)d_in[17];
    const float* outn_g = (const float*)d_in[18];
    const float* outn_b = (const float*)d_in[19];
    const float* sa_in_w  = (const float*)d_in[20];
    const float* sa_in_b  = (const float*)d_in[21];
    const float* sa_out_w = (const float*)d_in[22];
    const float* sa_out_b = (const float*)d_in[23];
    const float* ca_in_w  = (const float*)d_in[24];
    const float* ca_in_b  = (const float*)d_in[25];
    const float* ca_out_w = (const float*)d_in[26];
    const float* ca_out_b = (const float*)d_in[27];
    const float* ff_w1 = (const float*)d_in[28];
    const float* ff_b1 = (const float*)d_in[29];
    const float* ff_w2 = (const float*)d_in[30];
    const float* ff_b2 = (const float*)d_in[31];
    const float* ln1_g = (const float*)d_in[32];
    const float* ln1_b = (const float*)d_in[33];
    const float* ln2_g = (const float*)d_in[34];
    const float* ln2_b = (const float*)d_in[35];
    const float* ln3_g = (const float*)d_in[36];
    const float* ln3_b = (const float*)d_in[37];
    const float* proj_w = (const float*)d_in[38];
    const float* proj_b = (const float*)d_in[39];

    auto ALIGN = [](size_t b) { return (b + 255) & ~(size_t)255; };
    uintptr_t base = (uintptr_t)d_ws;
    uintptr_t cur = (base + 255) & ~(uintptr_t)255;
    auto alloc = [&](size_t bytes) -> char* {
        char* r = (char*)cur; cur += (bytes + 255) & ~(size_t)255; return r;
    };

    // ---------------- persistent allocations ----------------
    float* self_state = (float*)alloc((size_t)1024 * 512 * 4);
    bf16*  mems       = (bf16*) alloc((size_t)(26784 + 128) * 512 * 2);
    float* sel        = (float*)alloc((size_t)1024 * 512 * 4);
    bf16*  sel_ln_b   = (bf16*) alloc((size_t)1024 * 512 * 2);
    // bf16 weights
    bf16* w_emb   = (bf16*)alloc((size_t)4096 * 512 * 2);
    bf16* w_se1p  = (bf16*)alloc((size_t)512 * 576 * 2);
    bf16* w_be1p  = (bf16*)alloc((size_t)512 * 576 * 2);
    bf16* w_se2   = (bf16*)alloc((size_t)512 * 512 * 2);
    bf16* w_be2   = (bf16*)alloc((size_t)512 * 512 * 2);
    bf16* w_sain  = (bf16*)alloc((size_t)4 * 1536 * 512 * 2);
    bf16* w_saout = (bf16*)alloc((size_t)4 * 512 * 512 * 2);
    bf16* w_cain  = (bf16*)alloc((size_t)4 * 1536 * 512 * 2);
    bf16* w_caout = (bf16*)alloc((size_t)4 * 512 * 512 * 2);
    bf16* w_ff1   = (bf16*)alloc((size_t)4 * 2048 * 512 * 2);
    bf16* w_ff2   = (bf16*)alloc((size_t)4 * 2048 * 512 * 2);
    bf16* w_proj  = (bf16*)alloc((size_t)4096 * 512 * 2);
    uintptr_t big = cur;

    size_t setup_need =
        ALIGN((size_t)1024 * 576 * 2) + ALIGN((size_t)1024 * 512 * 2) + ALIGN((size_t)1024 * 512 * 4) +
        ALIGN((size_t)8192 * 576 * 2) + ALIGN((size_t)8192 * 512 * 2) + ALIGN((size_t)8192 * 512 * 4) +
        ALIGN((size_t)9216 * 512 * 4);
    auto chunk_need = [&](int c) -> size_t {
        return ALIGN((size_t)c * 1024 * 512 * 4)
             + ALIGN((size_t)c * 1024 * 512 * 2)
             + ALIGN((size_t)c * 1024 * 1536 * 2)
             + ALIGN((size_t)c * 1024 * 512 * 2)
             + ALIGN((size_t)c * 1024 * 512 * 2)
             + ALIGN((size_t)c * 1024 * 2048 * 2)
             + ALIGN(((size_t)c * 864 + 128) * 1024 * 2);
    };
    int CH = 0;
    if (ws_size > (size_t)(big - base) + 4096) {
        size_t avail = ws_size - (size_t)(big - base) - 4096;
        for (int c = 31; c >= 1; --c)
            if (setup_need <= avail && chunk_need(c) <= avail) { CH = c; break; }
    }
    if (!CH) {
        fill_kernel<<<(out_size + 255) / 256, 256, 0, stream>>>(out, out_size, 1e6f);
        return;
    }

    // ---------------- weight conversion ----------------
    auto cvt = [&](const float* s, bf16* d, size_t n) {
        int n4 = (int)(n >> 2);
        int blocks = (n4 + 255) / 256; if (blocks > 2048) blocks = 2048;
        cvtw_kernel<<<blocks, 256, 0, stream>>>(s, (unsigned short*)d, (int)n);
    };
    cvt(emb, w_emb, (size_t)4096 * 512);
    cvtpad_kernel<<<512, 256, 0, stream>>>(se_w1, w_se1p, 515);
    cvtpad_kernel<<<512, 256, 0, stream>>>(be_w1, w_be1p, 517);
    cvt(se_w2, w_se2, (size_t)512 * 512);
    cvt(be_w2, w_be2, (size_t)512 * 512);
    cvt(sa_in_w, w_sain, (size_t)4 * 1536 * 512);
    cvt(sa_out_w, w_saout, (size_t)4 * 512 * 512);
    cvt(ca_in_w, w_cain, (size_t)4 * 1536 * 512);
    cvt(ca_out_w, w_caout, (size_t)4 * 512 * 512);
    cvt(ff_w1, w_ff1, (size_t)4 * 2048 * 512);
    cvt(ff_w2, w_ff2, (size_t)4 * 2048 * 512);
    cvt(proj_w, w_proj, (size_t)4096 * 512);

    auto launch_mfma = [&](const bf16* A, const bf16* W, const float* bias,
                           void* C, int c_bf16, int M, int N, int K, int relu, int smode) {
        dim3 g(N / 128, (M + 127) / 128);
        mfma_gemm<<<g, 256, 0, stream>>>(A, W, bias, C, M, N, K, c_bf16, relu, smode);
    };

    // ---------------- setup: encoders, env, mems ----------------
    {
        uintptr_t sp = big;
        auto salloc = [&](size_t b) -> char* { char* r = (char*)sp; sp += ALIGN(b); return r; };
        bf16*  xcat_b = (bf16*) salloc((size_t)1024 * 576 * 2);
        bf16*  h1b    = (bf16*) salloc((size_t)1024 * 512 * 2);
        float* fused  = (float*)salloc((size_t)1024 * 512 * 4);
        bf16*  acat_b = (bf16*) salloc((size_t)8192 * 576 * 2);
        bf16*  ah1b   = (bf16*) salloc((size_t)8192 * 512 * 2);
        float* astate = (float*)salloc((size_t)8192 * 512 * 4);
        float* env    = (float*)salloc((size_t)9216 * 512 * 4);

        xcatb_kernel<<<1024, 128, 0, stream>>>(input_ids, ego, w_emb, xcat_b);
        launch_mfma(xcat_b, w_se1p, se_b1, h1b, 1, 1024, 512, 576, 1, 0);
        launch_mfma(h1b, w_se2, se_b2, fused, 0, 1024, 512, 512, 0, 0);
        ln_kernel<<<256, 256, 0, stream>>>(fused, in_g, in_b, self_state, (bf16*)nullptr, 1024);

        acatb_kernel<<<8192, 128, 0, stream>>>(atok, afeat, w_emb, acat_b);
        launch_mfma(acat_b, w_be1p, be_b1, ah1b, 1, 8192, 512, 576, 1, 0);
        launch_mfma(ah1b, w_be2, be_b2, astate, 0, 8192, 512, 512, 0, 0);
        env_ln_kernel<<<2304, 256, 0, stream>>>(astate, atok, emb, goal, mem_g, mem_b, env);
        mems_kernel<<<26784, 64, 0, stream>>>(env, mems);
    }

    // ---------------- decode ----------------
    {
        uintptr_t sp = big;
        auto salloc = [&](size_t b) -> char* { char* r = (char*)sp; sp += ALIGN(b); return r; };
        float* x     = (float*)salloc((size_t)CH * 1024 * 512 * 4);
        bf16*  xb    = (bf16*) salloc((size_t)CH * 1024 * 512 * 2);
        bf16*  qkv   = (bf16*) salloc((size_t)CH * 1024 * 1536 * 2);
        bf16*  araw  = (bf16*) salloc((size_t)CH * 1024 * 512 * 2);
        bf16*  brnch = (bf16*) salloc((size_t)CH * 1024 * 512 * 2);
        bf16*  ff1b  = (bf16*) salloc((size_t)CH * 1024 * 2048 * 2);
        bf16*  kv    = (bf16*) salloc(((size_t)CH * 864 + 128) * 1024 * 2);

        for (int m0 = 0; m0 < 31; m0 += CH) {
            int cm = (31 - m0) < CH ? (31 - m0) : CH;
            int Mr = cm * 1024;
            initx_kernel<<<cm * 512, 256, 0, stream>>>(self_state, x, xb, Mr * 128);
            for (int l = 0; l < 4; ++l) {
                launch_mfma(xb, w_sain + (size_t)l * 1536 * 512, sa_in_b + l * 1536,
                            qkv, 1, Mr, 1536, 512, 0, 0);
                self_attn_kernel<<<cm * 32 * 8, 256, 0, stream>>>(qkv, input_ids, araw, cm);
                launch_mfma(araw, w_saout + (size_t)l * 512 * 512, sa_out_b + l * 512,
                            brnch, 1, Mr, 512, 512, 0, 0);
                ln_res_kernel<<<(Mr + 3) / 4, 256, 0, stream>>>(x, brnch, ln1_g + l * 512, ln1_b + l * 512, xb, Mr);
                launch_mfma(xb, w_cain + (size_t)l * 1536 * 512, ca_in_b + l * 1536,
                            qkv, 1, Mr, 512, 512, 0, 0);
                launch_mfma(mems + (size_t)m0 * 864 * 512,
                            w_cain + (size_t)l * 1536 * 512 + (size_t)512 * 512,
                            ca_in_b + l * 1536 + 512,
                            kv, 1, cm * 864, 1024, 512, 0, 0);
                cross_attn_kernel<<<cm * 32 * 8, 256, 0, stream>>>(qkv, kv, araw, cm);
                launch_mfma(araw, w_caout + (size_t)l * 512 * 512, ca_out_b + l * 512,
                            brnch, 1, Mr, 512, 512, 0, 0);
                ln_res_kernel<<<(Mr + 3) / 4, 256, 0, stream>>>(x, brnch, ln2_g + l * 512, ln2_b + l * 512, xb, Mr);
                launch_mfma(xb, w_ff1 + (size_t)l * 2048 * 512, ff_b1 + l * 2048,
                            ff1b, 1, Mr, 2048, 512, 1, 0);
                launch_mfma(ff1b, w_ff2 + (size_t)l * 512 * 2048, ff_b2 + l * 512,
                            brnch, 1, Mr, 512, 2048, 0, 0);
                ln_res_kernel<<<(Mr + 3) / 4, 256, 0, stream>>>(x, brnch, ln3_g + l * 512, ln3_b + l * 512, xb, Mr);
            }
            sel_kernel<<<cm * 32, 128, 0, stream>>>(x, sel, m0, cm);
        }
    }

    // ---------------- final: LN + vocab projection (transposed store) ----------------
    ln_kernel<<<248, 256, 0, stream>>>(sel, outn_g, outn_b, (float*)nullptr, sel_ln_b, 992);
    launch_mfma(sel_ln_b, w_proj, proj_b, out, 0, 992, 4096, 512, 0, 1);
}

// Round 4
// 3445.910 us; speedup vs baseline: 5.9036x; 1.5632x over previous
//
#include <hip/hip_runtime.h>
#include <hip/hip_bf16.h>
#include <stdint.h>

typedef __hip_bfloat16 bf16;
typedef __attribute__((ext_vector_type(8))) short bf16x8;
typedef __attribute__((ext_vector_type(4))) float f32x4;

__device__ __forceinline__ float b2f(bf16 v) { return __bfloat162float(v); }
__device__ __forceinline__ bf16 f2b(float v) { return __float2bfloat16(v); }
__device__ __forceinline__ unsigned short f2bu(float v) {
    bf16 h = __float2bfloat16(v);
    return *(unsigned short*)&h;
}
__device__ __forceinline__ short f2bs(float v) {
    bf16 h = __float2bfloat16(v);
    return *(short*)&h;
}
__device__ __forceinline__ float su2f(unsigned short u) {
    unsigned int x = ((unsigned int)u) << 16;
    return *(float*)&x;
}

__device__ __forceinline__ void gload_lds16(const void* g, void* l) {
    __builtin_amdgcn_global_load_lds((const __attribute__((address_space(1))) void*)g,
                                     (__attribute__((address_space(3))) void*)l, 16, 0, 0);
}

// swizzled byte offset inside a [row][32 kk] bf16 LDS tile with 80B row stride.
// 16B block b = kk>>3 is XOR'd with (row&3): write and read use the same map.
__device__ __forceinline__ int swz_byte(int row, int kk) {
    return row * 80 + 2 * (kk & 7) + 16 * ((kk >> 3) ^ (row & 3));
}

// ---------------------------------------------------------------------------
// MFMA bf16 GEMM: C[M,N] = act(A[M,K]@W[N,K]^T + bias)
// 128x128 tile, BK=64, 4 waves. global_load_lds staging w/ XOR-swizzled source.
// Bijective XCD-aware block swizzle (m204) for L2 A-panel reuse.
// ---------------------------------------------------------------------------
__global__ __launch_bounds__(256) void mfma_gemm(
    const bf16* __restrict__ A, const bf16* __restrict__ W,
    const float* __restrict__ bias, void* __restrict__ C,
    int M, int N, int K, int c_bf16, int relu, int store_mode)
{
    __shared__ bf16 As[128 * 64];
    __shared__ bf16 Bs[128 * 64];
    const int gx = gridDim.x;
    const int nwg = gx * gridDim.y;
    const int orig = blockIdx.y * gx + blockIdx.x;
    const int qq = nwg >> 3, rr8 = nwg & 7;
    const int xcd = orig & 7, lid = orig >> 3;
    const int wgid = (xcd < rr8 ? xcd * (qq + 1) : rr8 * (qq + 1) + (xcd - rr8) * qq) + lid;
    const int m0 = (wgid / gx) * 128, n0 = (wgid % gx) * 128;

    const int tid = threadIdx.x;
    const int wave = tid >> 6, lane = tid & 63;
    const int wr = wave >> 1, wc = wave & 1;
    const int fr = lane & 15, fg = lane >> 4;
    f32x4 acc[4][4] = {};

    const int srow = lane >> 3;
    const int sunit = (lane & 7) ^ srow;

    for (int k0 = 0; k0 < K; k0 += 64) {
#pragma unroll
        for (int c = 0; c < 4; ++c) {
            const int chunk = wave * 4 + c;
            const int arow = m0 + chunk * 8 + srow;
            const int brow = n0 + chunk * 8 + srow;
            gload_lds16(A + (size_t)arow * K + k0 + sunit * 8, (char*)As + chunk * 1024);
            gload_lds16(W + (size_t)brow * K + k0 + sunit * 8, (char*)Bs + chunk * 1024);
        }
        __syncthreads();
#pragma unroll
        for (int kk = 0; kk < 64; kk += 32) {
            bf16x8 af[4], bw[4];
            const int bo = (kk + fg * 8) * 2;
#pragma unroll
            for (int t = 0; t < 4; ++t) {
                const int ra = wr * 64 + t * 16 + fr;
                af[t] = *(const bf16x8*)((const char*)As + ra * 128 + (bo ^ ((ra & 7) << 4)));
                const int rb = wc * 64 + t * 16 + fr;
                bw[t] = *(const bf16x8*)((const char*)Bs + rb * 128 + (bo ^ ((rb & 7) << 4)));
            }
#pragma unroll
            for (int mt = 0; mt < 4; ++mt)
#pragma unroll
                for (int nt = 0; nt < 4; ++nt)
                    acc[mt][nt] = __builtin_amdgcn_mfma_f32_16x16x32_bf16(
                        af[mt], bw[nt], acc[mt][nt], 0, 0, 0);
        }
        __syncthreads();
    }
#pragma unroll
    for (int mt = 0; mt < 4; ++mt) {
#pragma unroll
        for (int r = 0; r < 4; ++r) {
            const int m = m0 + wr * 64 + mt * 16 + fg * 4 + r;
            if (m >= M) continue;
            size_t orow = (size_t)m;
            if (store_mode == 1) orow = (size_t)(m & 31) * 31 + (m >> 5);
#pragma unroll
            for (int nt = 0; nt < 4; ++nt) {
                const int n = n0 + wc * 64 + nt * 16 + fr;
                float v = acc[mt][nt][r] + bias[n];
                if (relu) v = fmaxf(v, 0.f);
                if (c_bf16) ((bf16*)C)[orow * N + n] = f2b(v);
                else        ((float*)C)[orow * N + n] = v;
            }
        }
    }
}

// ---------------------------------------------------------------------------
// MFMA self-attention. Block = (mb, head-pair): grid nmb*4, 256 thr (4 waves).
// Wave (e = head within pair, qi = 16-row half). Q/K frags direct from global;
// V staged transposed in swizzled LDS; P via swizzled LDS.
// ---------------------------------------------------------------------------
__global__ __launch_bounds__(256) void self_attn_mfma(
    const bf16* __restrict__ qkv, const int* __restrict__ input_ids,
    bf16* __restrict__ attn_out)
{
    const int bid = blockIdx.x;
    const int hp = bid & 3;
    const int mb = bid >> 2;
    const int b = mb & 31;
    const size_t rowbase = (size_t)mb * 32;

    __shared__ __align__(16) char vt_raw[2][64 * 80];   // V^T per head: [d][kk]
    __shared__ __align__(16) char ps_raw[4][16 * 80];   // P per wave: [q][kk]
    __shared__ float kpmv[32];

    const int tid = threadIdx.x;
    {
        const int r = tid & 31, u = tid >> 5;   // V row r, 16B unit u
#pragma unroll
        for (int e2 = 0; e2 < 2; ++e2) {
            const int h = hp * 2 + e2;
            bf16x8 v8 = *(const bf16x8*)(qkv + (rowbase + r) * 1536 + 1024 + h * 64 + u * 8);
#pragma unroll
            for (int j = 0; j < 8; ++j)
                *(short*)(vt_raw[e2] + swz_byte(u * 8 + j, r)) = v8[j];
        }
    }
    if (tid < 32) kpmv[tid] = (input_ids[b * 32 + tid] == 0) ? -1e9f : 0.f;
    __syncthreads();

    const int wave = tid >> 6, lane = tid & 63;
    const int e = wave >> 1;
    const int h = hp * 2 + e;
    const int qi = wave & 1;
    const int c = lane & 15, fg = lane >> 4;

    // ---- QK^T (K=64 via 2 chunks) ----
    const bf16* qrow = qkv + (rowbase + qi * 16 + c) * 1536 + h * 64;
    bf16x8 af0 = *(const bf16x8*)(qrow + fg * 8);
    bf16x8 af1 = *(const bf16x8*)(qrow + 32 + fg * 8);
    f32x4 s[2];
#pragma unroll
    for (int kj = 0; kj < 2; ++kj) {
        const bf16* krow = qkv + (rowbase + kj * 16 + c) * 1536 + 512 + h * 64;
        bf16x8 b0 = *(const bf16x8*)(krow + fg * 8);
        bf16x8 b1 = *(const bf16x8*)(krow + 32 + fg * 8);
        f32x4 a = {};
        a = __builtin_amdgcn_mfma_f32_16x16x32_bf16(af0, b0, a, 0, 0, 0);
        a = __builtin_amdgcn_mfma_f32_16x16x32_bf16(af1, b1, a, 0, 0, 0);
        s[kj] = a;
    }

    // ---- masked softmax (rows = fg*4+r of this 16-row half) ----
#pragma unroll
    for (int r = 0; r < 4; ++r) {
        const int qg = qi * 16 + fg * 4 + r;
        float v0 = s[0][r] * 0.125f + kpmv[c];
        float v1 = s[1][r] * 0.125f + kpmv[16 + c];
        if (c > qg) v0 = -1e9f;
        if (16 + c > qg) v1 = -1e9f;
        float m = fmaxf(v0, v1);
        m = fmaxf(m, __shfl_xor(m, 1)); m = fmaxf(m, __shfl_xor(m, 2));
        m = fmaxf(m, __shfl_xor(m, 4)); m = fmaxf(m, __shfl_xor(m, 8));
        float e0 = __expf(v0 - m), e1 = __expf(v1 - m);
        float sm = e0 + e1;
        sm += __shfl_xor(sm, 1); sm += __shfl_xor(sm, 2);
        sm += __shfl_xor(sm, 4); sm += __shfl_xor(sm, 8);
        float inv = 1.f / sm;
        *(short*)(ps_raw[wave] + swz_byte(fg * 4 + r, c))      = f2bs(e0 * inv);
        *(short*)(ps_raw[wave] + swz_byte(fg * 4 + r, 16 + c)) = f2bs(e1 * inv);
    }

    // ---- PV (K=32, one MFMA per 16-d tile) ----
    bf16x8 pa = *(const bf16x8*)(ps_raw[wave] + c * 80 + 16 * (fg ^ (c & 3)));
    f32x4 o[4];
#pragma unroll
    for (int dj = 0; dj < 4; ++dj) {
        bf16x8 bv = *(const bf16x8*)(vt_raw[e] + (dj * 16 + c) * 80 + 16 * (fg ^ (c & 3)));
        f32x4 a = {};
        o[dj] = __builtin_amdgcn_mfma_f32_16x16x32_bf16(pa, bv, a, 0, 0, 0);
    }
#pragma unroll
    for (int dj = 0; dj < 4; ++dj)
#pragma unroll
        for (int r = 0; r < 4; ++r)
            attn_out[(rowbase + qi * 16 + fg * 4 + r) * 512 + h * 64 + dj * 16 + c] = f2b(o[dj][r]);
}

// ---------------------------------------------------------------------------
// MFMA cross-attention: LK=27 (padded to 32, masked). q stride 512, kv 1024.
// qshared: q has only 1024 rows (layer 0), indexed by (mb&31).
// ---------------------------------------------------------------------------
__global__ __launch_bounds__(256) void cross_attn_mfma(
    const bf16* __restrict__ q, int qshared, const bf16* __restrict__ kv,
    bf16* __restrict__ attn_out)
{
    const int bid = blockIdx.x;
    const int hp = bid & 3;
    const int mb = bid >> 2;
    const size_t qb = (size_t)(qshared ? (mb & 31) : mb) * 32;
    const size_t kvb = (size_t)mb * 27;
    const size_t ob = (size_t)mb * 32;

    __shared__ __align__(16) char vt_raw[2][64 * 80];
    __shared__ __align__(16) char ps_raw[4][16 * 80];

    const int tid = threadIdx.x;
    {
        const int r = tid & 31, u = tid >> 5;
#pragma unroll
        for (int e2 = 0; e2 < 2; ++e2) {
            const int h = hp * 2 + e2;
            bf16x8 v8 = *(const bf16x8*)(kv + (kvb + r) * 1024 + 512 + h * 64 + u * 8);
#pragma unroll
            for (int j = 0; j < 8; ++j)
                *(short*)(vt_raw[e2] + swz_byte(u * 8 + j, r)) = v8[j];
        }
    }
    __syncthreads();

    const int wave = tid >> 6, lane = tid & 63;
    const int e = wave >> 1;
    const int h = hp * 2 + e;
    const int qi = wave & 1;
    const int c = lane & 15, fg = lane >> 4;

    const bf16* qrow = q + (qb + qi * 16 + c) * 512 + h * 64;
    bf16x8 af0 = *(const bf16x8*)(qrow + fg * 8);
    bf16x8 af1 = *(const bf16x8*)(qrow + 32 + fg * 8);
    f32x4 s[2];
#pragma unroll
    for (int kj = 0; kj < 2; ++kj) {
        const bf16* krow = kv + (kvb + kj * 16 + c) * 1024 + h * 64;
        bf16x8 b0 = *(const bf16x8*)(krow + fg * 8);
        bf16x8 b1 = *(const bf16x8*)(krow + 32 + fg * 8);
        f32x4 a = {};
        a = __builtin_amdgcn_mfma_f32_16x16x32_bf16(af0, b0, a, 0, 0, 0);
        a = __builtin_amdgcn_mfma_f32_16x16x32_bf16(af1, b1, a, 0, 0, 0);
        s[kj] = a;
    }
#pragma unroll
    for (int r = 0; r < 4; ++r) {
        float v0 = s[0][r] * 0.125f;
        float v1 = (16 + c < 27) ? s[1][r] * 0.125f : -1e9f;
        float m = fmaxf(v0, v1);
        m = fmaxf(m, __shfl_xor(m, 1)); m = fmaxf(m, __shfl_xor(m, 2));
        m = fmaxf(m, __shfl_xor(m, 4)); m = fmaxf(m, __shfl_xor(m, 8));
        float e0 = __expf(v0 - m), e1 = __expf(v1 - m);
        float sm = e0 + e1;
        sm += __shfl_xor(sm, 1); sm += __shfl_xor(sm, 2);
        sm += __shfl_xor(sm, 4); sm += __shfl_xor(sm, 8);
        float inv = 1.f / sm;
        *(short*)(ps_raw[wave] + swz_byte(fg * 4 + r, c))      = f2bs(e0 * inv);
        *(short*)(ps_raw[wave] + swz_byte(fg * 4 + r, 16 + c)) = f2bs(e1 * inv);
    }
    bf16x8 pa = *(const bf16x8*)(ps_raw[wave] + c * 80 + 16 * (fg ^ (c & 3)));
    f32x4 o[4];
#pragma unroll
    for (int dj = 0; dj < 4; ++dj) {
        bf16x8 bv = *(const bf16x8*)(vt_raw[e] + (dj * 16 + c) * 80 + 16 * (fg ^ (c & 3)));
        f32x4 a = {};
        o[dj] = __builtin_amdgcn_mfma_f32_16x16x32_bf16(pa, bv, a, 0, 0, 0);
    }
#pragma unroll
    for (int dj = 0; dj < 4; ++dj)
#pragma unroll
        for (int r = 0; r < 4; ++r)
            attn_out[(ob + qi * 16 + fg * 4 + r) * 512 + h * 64 + dj * 16 + c] = f2b(o[dj][r]);
}

// ---------------------------------------------------------------------------
// LayerNorm over D=512, vectorized. Optional f32 / bf16 outputs.
// ---------------------------------------------------------------------------
__global__ __launch_bounds__(256) void ln_kernel(
    const float* __restrict__ x, const float* __restrict__ g,
    const float* __restrict__ b_, float* __restrict__ outf,
    bf16* __restrict__ outb, int rows)
{
    int row = blockIdx.x * 4 + (threadIdx.x >> 6);
    if (row >= rows) return;
    int lane = threadIdx.x & 63;
    const float4* xr = (const float4*)(x + (size_t)row * 512);
    float4 v[2];
    float sum = 0.f;
#pragma unroll
    for (int j = 0; j < 2; ++j) {
        v[j] = xr[lane + 64 * j];
        sum += v[j].x + v[j].y + v[j].z + v[j].w;
    }
    for (int o = 32; o; o >>= 1) sum += __shfl_xor(sum, o, 64);
    float mean = sum * (1.f / 512.f);
    float vs = 0.f;
#pragma unroll
    for (int j = 0; j < 2; ++j) {
        float dx = v[j].x - mean, dy = v[j].y - mean, dz = v[j].z - mean, dw = v[j].w - mean;
        vs += dx * dx + dy * dy + dz * dz + dw * dw;
    }
    for (int o = 32; o; o >>= 1) vs += __shfl_xor(vs, o, 64);
    float rstd = rsqrtf(vs * (1.f / 512.f) + 1e-5f);
#pragma unroll
    for (int j = 0; j < 2; ++j) {
        int u = lane + 64 * j;
        float4 g4 = ((const float4*)g)[u];
        float4 b4 = ((const float4*)b_)[u];
        float4 o4;
        o4.x = (v[j].x - mean) * rstd * g4.x + b4.x;
        o4.y = (v[j].y - mean) * rstd * g4.y + b4.y;
        o4.z = (v[j].z - mean) * rstd * g4.z + b4.z;
        o4.w = (v[j].w - mean) * rstd * g4.w + b4.w;
        if (outf) ((float4*)(outf + (size_t)row * 512))[u] = o4;
        if (outb) {
            ushort4 s4 = { f2bu(o4.x), f2bu(o4.y), f2bu(o4.z), f2bu(o4.w) };
            ((ushort4*)(outb + (size_t)row * 512))[u] = s4;
        }
    }
}

// xout = LN(xin[row&mask] + br[row]); writes f32 xout and bf16 xbout.
__global__ __launch_bounds__(256) void ln_res2_kernel(
    const float* __restrict__ xin, int rowmask, const bf16* __restrict__ br,
    const float* __restrict__ g, const float* __restrict__ b_,
    float* __restrict__ xout, bf16* __restrict__ xbout, int rows)
{
    int row = blockIdx.x * 4 + (threadIdx.x >> 6);
    if (row >= rows) return;
    int lane = threadIdx.x & 63;
    const float4* xr = (const float4*)(xin + (size_t)(row & rowmask) * 512);
    const ushort4* brr = (const ushort4*)(br + (size_t)row * 512);
    float4 v[2];
    float sum = 0.f;
#pragma unroll
    for (int j = 0; j < 2; ++j) {
        int u = lane + 64 * j;
        float4 a = xr[u];
        ushort4 s4 = brr[u];
        a.x += su2f(s4.x); a.y += su2f(s4.y); a.z += su2f(s4.z); a.w += su2f(s4.w);
        v[j] = a;
        sum += a.x + a.y + a.z + a.w;
    }
    for (int o = 32; o; o >>= 1) sum += __shfl_xor(sum, o, 64);
    float mean = sum * (1.f / 512.f);
    float vs = 0.f;
#pragma unroll
    for (int j = 0; j < 2; ++j) {
        float dx = v[j].x - mean, dy = v[j].y - mean, dz = v[j].z - mean, dw = v[j].w - mean;
        vs += dx * dx + dy * dy + dz * dz + dw * dw;
    }
    for (int o = 32; o; o >>= 1) vs += __shfl_xor(vs, o, 64);
    float rstd = rsqrtf(vs * (1.f / 512.f) + 1e-5f);
#pragma unroll
    for (int j = 0; j < 2; ++j) {
        int u = lane + 64 * j;
        float4 g4 = ((const float4*)g)[u];
        float4 b4 = ((const float4*)b_)[u];
        float4 o4;
        o4.x = (v[j].x - mean) * rstd * g4.x + b4.x;
        o4.y = (v[j].y - mean) * rstd * g4.y + b4.y;
        o4.z = (v[j].z - mean) * rstd * g4.z + b4.z;
        o4.w = (v[j].w - mean) * rstd * g4.w + b4.w;
        ((float4*)(xout + (size_t)row * 512))[u] = o4;
        ushort4 s4 = { f2bu(o4.x), f2bu(o4.y), f2bu(o4.z), f2bu(o4.w) };
        ((ushort4*)(xbout + (size_t)row * 512))[u] = s4;
    }
}

// env row build + LN (mem_g/mem_b). rows = 9216.
__global__ __launch_bounds__(256) void env_ln_kernel(
    const float* __restrict__ astate, const int* __restrict__ atok,
    const float* __restrict__ emb, const int* __restrict__ goal,
    const float* __restrict__ g, const float* __restrict__ b_, float* __restrict__ env)
{
    int row = blockIdx.x * 4 + (threadIdx.x >> 6);
    if (row >= 9216) return;
    int lane = threadIdx.x & 63;
    int s9 = row % 9;
    int bt = row / 9;
    float4 v[2];
    if (s9 < 8) {
        int ar = bt * 8 + s9;
        float msk = (atok[ar] != -1) ? 1.f : 0.f;
#pragma unroll
        for (int j = 0; j < 2; ++j) {
            float4 a = ((const float4*)(astate + (size_t)ar * 512))[lane + 64 * j];
            a.x *= msk; a.y *= msk; a.z *= msk; a.w *= msk;
            v[j] = a;
        }
    } else {
        int gi = goal[bt >> 5];
#pragma unroll
        for (int j = 0; j < 2; ++j)
            v[j] = ((const float4*)(emb + (size_t)gi * 512))[lane + 64 * j];
    }
    float sum = 0.f;
#pragma unroll
    for (int j = 0; j < 2; ++j) sum += v[j].x + v[j].y + v[j].z + v[j].w;
    for (int o = 32; o; o >>= 1) sum += __shfl_xor(sum, o, 64);
    float mean = sum * (1.f / 512.f);
    float vs = 0.f;
#pragma unroll
    for (int j = 0; j < 2; ++j) {
        float dx = v[j].x - mean, dy = v[j].y - mean, dz = v[j].z - mean, dw = v[j].w - mean;
        vs += dx * dx + dy * dy + dz * dz + dw * dw;
    }
    for (int o = 32; o; o >>= 1) vs += __shfl_xor(vs, o, 64);
    float rstd = rsqrtf(vs * (1.f / 512.f) + 1e-5f);
#pragma unroll
    for (int j = 0; j < 2; ++j) {
        int u = lane + 64 * j;
        float4 g4 = ((const float4*)g)[u];
        float4 b4 = ((const float4*)b_)[u];
        float4 o4;
        o4.x = (v[j].x - mean) * rstd * g4.x + b4.x;
        o4.y = (v[j].y - mean) * rstd * g4.y + b4.y;
        o4.z = (v[j].z - mean) * rstd * g4.z + b4.z;
        o4.w = (v[j].w - mean) * rstd * g4.w + b4.w;
        ((float4*)(env + (size_t)row * 512))[u] = o4;
    }
}

__global__ void mems_kernel(const float* __restrict__ env, bf16* __restrict__ mems)
{
    int row = blockIdx.x;               // 26784
    int j = row % 27;
    int mb = row / 27;
    int m = mb >> 5, b = mb & 31;
    int gidx = j / 9, sp = j % 9;
    int t = m - 1 + gidx;
    t = t < 0 ? 0 : (t > 31 ? 31 : t);
    const float4* src = (const float4*)(env + ((size_t)(b * 32 + t) * 9 + sp) * 512);
    ushort4* dst = (ushort4*)(mems + (size_t)row * 512);
    int tid = threadIdx.x;
#pragma unroll
    for (int k = 0; k < 2; ++k) {
        int u = tid + 64 * k;
        float4 a = src[u];
        ushort4 s4 = { f2bu(a.x), f2bu(a.y), f2bu(a.z), f2bu(a.w) };
        dst[u] = s4;
    }
}

__global__ void xcatb_kernel(const int* __restrict__ ids, const float* __restrict__ ego,
                             const bf16* __restrict__ emb_b, bf16* __restrict__ xcat)
{
    int row = blockIdx.x;   // 1024
    int tid = threadIdx.x;  // 128
    int b = row >> 5;
    int id = ids[row];
    bf16x8* dst = (bf16x8*)(xcat + (size_t)row * 576);
    if (tid < 64) {
        dst[tid] = ((const bf16x8*)(emb_b + (size_t)id * 512))[tid];
    } else if (tid == 64) {
        bf16x8 u = {};
        u[0] = f2bs(ego[b * 3 + 0]);
        u[1] = f2bs(ego[b * 3 + 1]);
        u[2] = f2bs(ego[b * 3 + 2]);
        dst[64] = u;
    } else if (tid < 72) {
        bf16x8 z = {};
        dst[tid] = z;
    }
}

__global__ void acatb_kernel(const int* __restrict__ atok, const float* __restrict__ afeat,
                             const bf16* __restrict__ emb_b, bf16* __restrict__ acat)
{
    int row = blockIdx.x;   // 8192
    int tid = threadIdx.x;  // 128
    int tok = atok[row];
    int id = (tok != -1) ? tok : 0;
    bf16x8* dst = (bf16x8*)(acat + (size_t)row * 576);
    if (tid < 64) {
        dst[tid] = ((const bf16x8*)(emb_b + (size_t)id * 512))[tid];
    } else if (tid == 64) {
        bf16x8 u = {};
#pragma unroll
        for (int e = 0; e < 5; ++e) u[e] = f2bs(afeat[(size_t)row * 5 + e]);
        dst[64] = u;
    } else if (tid < 72) {
        bf16x8 z = {};
        dst[tid] = z;
    }
}

__global__ void sel_kernel(const float* __restrict__ x, float* __restrict__ sel, int m0, int cm)
{
    int row = blockIdx.x;   // cm*32
    int ml = row >> 5, b = row & 31;
    int m = m0 + ml;
    const float4* src = (const float4*)(x + ((size_t)(ml * 32 + b) * 32 + (m + 1)) * 512);
    float4* dst = (float4*)(sel + ((size_t)m * 32 + b) * 512);
    dst[threadIdx.x] = src[threadIdx.x];
}

__global__ void fill_kernel(float* __restrict__ o, int n, float v)
{
    int i = blockIdx.x * 256 + threadIdx.x;
    if (i < n) o[i] = v;
}

__global__ void cvtw_kernel(const float* __restrict__ s, unsigned short* __restrict__ d, int n)
{
    int n4 = n >> 2;
    int stride = gridDim.x * blockDim.x;
    for (int i = blockIdx.x * blockDim.x + threadIdx.x; i < n4; i += stride) {
        float4 v = ((const float4*)s)[i];
        ushort4 u = { f2bu(v.x), f2bu(v.y), f2bu(v.z), f2bu(v.w) };
        ((ushort4*)d)[i] = u;
    }
}

__global__ void cvtpad_kernel(const float* __restrict__ s, bf16* __restrict__ d, int Ks)
{
    int row = blockIdx.x;
    int tid = threadIdx.x;
    for (int c = tid; c < 576; c += 256) {
        float v = (c < Ks) ? s[(size_t)row * Ks + c] : 0.f;
        d[(size_t)row * 576 + c] = f2b(v);
    }
}

// ---------------------------------------------------------------------------
extern "C" void kernel_launch(void* const* d_in, const int* in_sizes, int n_in,
                              void* d_out, int out_size, void* d_ws, size_t ws_size,
                              hipStream_t stream)
{
    float* out = (float*)d_out;
    if (n_in < 40) {
        fill_kernel<<<(out_size + 255) / 256, 256, 0, stream>>>(out, out_size, 1e6f);
        return;
    }
    const int*   input_ids = (const int*)d_in[0];
    const float* ego       = (const float*)d_in[1];
    const int*   atok      = (const int*)d_in[2];
    const float* afeat     = (const float*)d_in[3];
    const int*   goal      = (const int*)d_in[4];
    const float* emb       = (const float*)d_in[5];
    const float* se_w1 = (const float*)d_in[6];
    const float* se_b1 = (const float*)d_in[7];
    const float* se_w2 = (const float*)d_in[8];
    const float* se_b2 = (const float*)d_in[9];
    const float* be_w1 = (const float*)d_in[10];
    const float* be_b1 = (const float*)d_in[11];
    const float* be_w2 = (const float*)d_in[12];
    const float* be_b2 = (const float*)d_in[13];
    const float* in_g  = (const float*)d_in[14];
    const float* in_b  = (const float*)d_in[15];
    const float* mem_g = (const float*)d_in[16];
    const float* mem_b = (const float*)d_in[17];
    const float* outn_g = (const float*)d_in[18];
    const float* outn_b = (const float*)d_in[19];
    const float* sa_in_w  = (const float*)d_in[20];
    const float* sa_in_b  = (const float*)d_in[21];
    const float* sa_out_w = (const float*)d_in[22];
    const float* sa_out_b = (const float*)d_in[23];
    const float* ca_in_w  = (const float*)d_in[24];
    const float* ca_in_b  = (const float*)d_in[25];
    const float* ca_out_w = (const float*)d_in[26];
    const float* ca_out_b = (const float*)d_in[27];
    const float* ff_w1 = (const float*)d_in[28];
    const float* ff_b1 = (const float*)d_in[29];
    const float* ff_w2 = (const float*)d_in[30];
    const float* ff_b2 = (const float*)d_in[31];
    const float* ln1_g = (const float*)d_in[32];
    const float* ln1_b = (const float*)d_in[33];
    const float* ln2_g = (const float*)d_in[34];
    const float* ln2_b = (const float*)d_in[35];
    const float* ln3_g = (const float*)d_in[36];
    const float* ln3_b = (const float*)d_in[37];
    const float* proj_w = (const float*)d_in[38];
    const float* proj_b = (const float*)d_in[39];

    auto ALIGN = [](size_t b) { return (b + 255) & ~(size_t)255; };
    uintptr_t base = (uintptr_t)d_ws;
    uintptr_t cur = (base + 255) & ~(uintptr_t)255;
    auto alloc = [&](size_t bytes) -> char* {
        char* r = (char*)cur; cur += (bytes + 255) & ~(size_t)255; return r;
    };

    // ---------------- persistent allocations ----------------
    float* self_state = (float*)alloc((size_t)1024 * 512 * 4);
    bf16*  ss_b       = (bf16*) alloc((size_t)1024 * 512 * 2);
    float* x0         = (float*)alloc((size_t)1024 * 512 * 4);
    bf16*  xb0        = (bf16*) alloc((size_t)1024 * 512 * 2);
    bf16*  q0b        = (bf16*) alloc((size_t)1024 * 512 * 2);
    bf16*  qkv0       = (bf16*) alloc((size_t)1024 * 1536 * 2);
    bf16*  araw0      = (bf16*) alloc((size_t)1024 * 512 * 2);
    bf16*  brnch0     = (bf16*) alloc((size_t)1024 * 512 * 2);
    bf16*  mems       = (bf16*) alloc((size_t)(26784 + 128) * 512 * 2);
    float* sel        = (float*)alloc((size_t)1024 * 512 * 4);
    bf16*  sel_ln_b   = (bf16*) alloc((size_t)1024 * 512 * 2);
    // bf16 weights
    bf16* w_emb   = (bf16*)alloc((size_t)4096 * 512 * 2);
    bf16* w_se1p  = (bf16*)alloc((size_t)512 * 576 * 2);
    bf16* w_be1p  = (bf16*)alloc((size_t)512 * 576 * 2);
    bf16* w_se2   = (bf16*)alloc((size_t)512 * 512 * 2);
    bf16* w_be2   = (bf16*)alloc((size_t)512 * 512 * 2);
    bf16* w_sain  = (bf16*)alloc((size_t)4 * 1536 * 512 * 2);
    bf16* w_saout = (bf16*)alloc((size_t)4 * 512 * 512 * 2);
    bf16* w_cain  = (bf16*)alloc((size_t)4 * 1536 * 512 * 2);
    bf16* w_caout = (bf16*)alloc((size_t)4 * 512 * 512 * 2);
    bf16* w_ff1   = (bf16*)alloc((size_t)4 * 2048 * 512 * 2);
    bf16* w_ff2   = (bf16*)alloc((size_t)4 * 2048 * 512 * 2);
    bf16* w_proj  = (bf16*)alloc((size_t)4096 * 512 * 2);
    uintptr_t big = cur;

    size_t setup_need =
        ALIGN((size_t)1024 * 576 * 2) + ALIGN((size_t)1024 * 512 * 2) + ALIGN((size_t)1024 * 512 * 4) +
        ALIGN((size_t)8192 * 576 * 2) + ALIGN((size_t)8192 * 512 * 2) + ALIGN((size_t)8192 * 512 * 4) +
        ALIGN((size_t)9216 * 512 * 4);
    auto chunk_need = [&](int c) -> size_t {
        return ALIGN((size_t)c * 1024 * 512 * 4)
             + ALIGN((size_t)c * 1024 * 512 * 2)
             + ALIGN((size_t)c * 1024 * 1536 * 2)
             + ALIGN((size_t)c * 1024 * 512 * 2)
             + ALIGN((size_t)c * 1024 * 512 * 2)
             + ALIGN((size_t)c * 1024 * 2048 * 2)
             + ALIGN(((size_t)c * 864 + 128) * 1024 * 2);
    };
    int CH = 0;
    if (ws_size > (size_t)(big - base) + 4096) {
        size_t avail = ws_size - (size_t)(big - base) - 4096;
        for (int c = 31; c >= 1; --c)
            if (setup_need <= avail && chunk_need(c) <= avail) { CH = c; break; }
    }
    if (!CH) {
        fill_kernel<<<(out_size + 255) / 256, 256, 0, stream>>>(out, out_size, 1e6f);
        return;
    }

    // ---------------- weight conversion ----------------
    auto cvt = [&](const float* s, bf16* d, size_t n) {
        int n4 = (int)(n >> 2);
        int blocks = (n4 + 255) / 256; if (blocks > 2048) blocks = 2048;
        cvtw_kernel<<<blocks, 256, 0, stream>>>(s, (unsigned short*)d, (int)n);
    };
    cvt(emb, w_emb, (size_t)4096 * 512);
    cvtpad_kernel<<<512, 256, 0, stream>>>(se_w1, w_se1p, 515);
    cvtpad_kernel<<<512, 256, 0, stream>>>(be_w1, w_be1p, 517);
    cvt(se_w2, w_se2, (size_t)512 * 512);
    cvt(be_w2, w_be2, (size_t)512 * 512);
    cvt(sa_in_w, w_sain, (size_t)4 * 1536 * 512);
    cvt(sa_out_w, w_saout, (size_t)4 * 512 * 512);
    cvt(ca_in_w, w_cain, (size_t)4 * 1536 * 512);
    cvt(ca_out_w, w_caout, (size_t)4 * 512 * 512);
    cvt(ff_w1, w_ff1, (size_t)4 * 2048 * 512);
    cvt(ff_w2, w_ff2, (size_t)4 * 2048 * 512);
    cvt(proj_w, w_proj, (size_t)4096 * 512);

    auto launch_mfma = [&](const bf16* A, const bf16* W, const float* bias,
                           void* C, int c_bf16, int M, int N, int K, int relu, int smode) {
        dim3 g(N / 128, (M + 127) / 128);
        mfma_gemm<<<g, 256, 0, stream>>>(A, W, bias, C, M, N, K, c_bf16, relu, smode);
    };

    // ---------------- setup: encoders, env, mems ----------------
    {
        uintptr_t sp = big;
        auto salloc = [&](size_t b) -> char* { char* r = (char*)sp; sp += ALIGN(b); return r; };
        bf16*  xcat_b = (bf16*) salloc((size_t)1024 * 576 * 2);
        bf16*  h1b    = (bf16*) salloc((size_t)1024 * 512 * 2);
        float* fused  = (float*)salloc((size_t)1024 * 512 * 4);
        bf16*  acat_b = (bf16*) salloc((size_t)8192 * 576 * 2);
        bf16*  ah1b   = (bf16*) salloc((size_t)8192 * 512 * 2);
        float* astate = (float*)salloc((size_t)8192 * 512 * 4);
        float* env    = (float*)salloc((size_t)9216 * 512 * 4);

        xcatb_kernel<<<1024, 128, 0, stream>>>(input_ids, ego, w_emb, xcat_b);
        launch_mfma(xcat_b, w_se1p, se_b1, h1b, 1, 1024, 512, 576, 1, 0);
        launch_mfma(h1b, w_se2, se_b2, fused, 0, 1024, 512, 512, 0, 0);
        ln_kernel<<<256, 256, 0, stream>>>(fused, in_g, in_b, self_state, ss_b, 1024);

        acatb_kernel<<<8192, 128, 0, stream>>>(atok, afeat, w_emb, acat_b);
        launch_mfma(acat_b, w_be1p, be_b1, ah1b, 1, 8192, 512, 576, 1, 0);
        launch_mfma(ah1b, w_be2, be_b2, astate, 0, 8192, 512, 512, 0, 0);
        env_ln_kernel<<<2304, 256, 0, stream>>>(astate, atok, emb, goal, mem_g, mem_b, env);
        mems_kernel<<<26784, 64, 0, stream>>>(env, mems);
    }

    // ---------------- layer-0 shared prefix (x identical across the 31 mems) ----
    launch_mfma(ss_b, w_sain, sa_in_b, qkv0, 1, 1024, 1536, 512, 0, 0);
    self_attn_mfma<<<32 * 4, 256, 0, stream>>>(qkv0, input_ids, araw0);
    launch_mfma(araw0, w_saout, sa_out_b, brnch0, 1, 1024, 512, 512, 0, 0);
    ln_res2_kernel<<<256, 256, 0, stream>>>(self_state, 0x7fffffff, brnch0,
                                            ln1_g, ln1_b, x0, xb0, 1024);
    launch_mfma(xb0, w_cain, ca_in_b, q0b, 1, 1024, 512, 512, 0, 0);

    // ---------------- decode ----------------
    {
        uintptr_t sp = big;
        auto salloc = [&](size_t b) -> char* { char* r = (char*)sp; sp += ALIGN(b); return r; };
        float* x     = (float*)salloc((size_t)CH * 1024 * 512 * 4);
        bf16*  xb    = (bf16*) salloc((size_t)CH * 1024 * 512 * 2);
        bf16*  qkv   = (bf16*) salloc((size_t)CH * 1024 * 1536 * 2);
        bf16*  araw  = (bf16*) salloc((size_t)CH * 1024 * 512 * 2);
        bf16*  brnch = (bf16*) salloc((size_t)CH * 1024 * 512 * 2);
        bf16*  ff1b  = (bf16*) salloc((size_t)CH * 1024 * 2048 * 2);
        bf16*  kv    = (bf16*) salloc(((size_t)CH * 864 + 128) * 1024 * 2);

        for (int m0 = 0; m0 < 31; m0 += CH) {
            int cm = (31 - m0) < CH ? (31 - m0) : CH;
            int Mr = cm * 1024;
            // --- layer 0 (shared self-attn prefix precomputed) ---
            launch_mfma(mems + (size_t)m0 * 864 * 512, w_cain + (size_t)512 * 512,
                        ca_in_b + 512, kv, 1, cm * 864, 1024, 512, 0, 0);
            cross_attn_mfma<<<cm * 32 * 4, 256, 0, stream>>>(q0b, 1, kv, araw);
            launch_mfma(araw, w_caout, ca_out_b, brnch, 1, Mr, 512, 512, 0, 0);
            ln_res2_kernel<<<(Mr + 3) / 4, 256, 0, stream>>>(x0, 1023, brnch,
                                                             ln2_g, ln2_b, x, xb, Mr);
            launch_mfma(xb, w_ff1, ff_b1, ff1b, 1, Mr, 2048, 512, 1, 0);
            launch_mfma(ff1b, w_ff2, ff_b2, brnch, 1, Mr, 512, 2048, 0, 0);
            ln_res2_kernel<<<(Mr + 3) / 4, 256, 0, stream>>>(x, 0x7fffffff, brnch,
                                                             ln3_g, ln3_b, x, xb, Mr);
            // --- layers 1..3 ---
            for (int l = 1; l < 4; ++l) {
                launch_mfma(xb, w_sain + (size_t)l * 1536 * 512, sa_in_b + l * 1536,
                            qkv, 1, Mr, 1536, 512, 0, 0);
                self_attn_mfma<<<cm * 32 * 4, 256, 0, stream>>>(qkv, input_ids, araw);
                launch_mfma(araw, w_saout + (size_t)l * 512 * 512, sa_out_b + l * 512,
                            brnch, 1, Mr, 512, 512, 0, 0);
                ln_res2_kernel<<<(Mr + 3) / 4, 256, 0, stream>>>(x, 0x7fffffff, brnch,
                                                                 ln1_g + l * 512, ln1_b + l * 512, x, xb, Mr);
                launch_mfma(xb, w_cain + (size_t)l * 1536 * 512, ca_in_b + l * 1536,
                            qkv, 1, Mr, 512, 512, 0, 0);
                launch_mfma(mems + (size_t)m0 * 864 * 512,
                            w_cain + (size_t)l * 1536 * 512 + (size_t)512 * 512,
                            ca_in_b + l * 1536 + 512,
                            kv, 1, cm * 864, 1024, 512, 0, 0);
                cross_attn_mfma<<<cm * 32 * 4, 256, 0, stream>>>(qkv, 0, kv, araw);
                launch_mfma(araw, w_caout + (size_t)l * 512 * 512, ca_out_b + l * 512,
                            brnch, 1, Mr, 512, 512, 0, 0);
                ln_res2_kernel<<<(Mr + 3) / 4, 256, 0, stream>>>(x, 0x7fffffff, brnch,
                                                                 ln2_g + l * 512, ln2_b + l * 512, x, xb, Mr);
                launch_mfma(xb, w_ff1 + (size_t)l * 2048 * 512, ff_b1 + l * 2048,
                            ff1b, 1, Mr, 2048, 512, 1, 0);
                launch_mfma(ff1b, w_ff2 + (size_t)l * 512 * 2048, ff_b2 + l * 512,
                            brnch, 1, Mr, 512, 2048, 0, 0);
                ln_res2_kernel<<<(Mr + 3) / 4, 256, 0, stream>>>(x, 0x7fffffff, brnch,
                                                                 ln3_g + l * 512, ln3_b + l * 512, x, xb, Mr);
            }
            sel_kernel<<<cm * 32, 128, 0, stream>>>(x, sel, m0, cm);
        }
    }

    // ---------------- final: LN + vocab projection (transposed store) ----------------
    ln_kernel<<<248, 256, 0, stream>>>(sel, outn_g, outn_b, (float*)nullptr, sel_ln_b, 992);
    launch_mfma(sel_ln_b, w_proj, proj_b, out, 0, 992, 4096, 512, 0, 1);
}